// Round 6
// baseline (1063.824 us; speedup 1.0000x reference)
//
#include <hip/hip_runtime.h>
#include <hip/hip_bf16.h>

typedef unsigned short ushort_t;
typedef __attribute__((ext_vector_type(8))) __bf16 bf16x8;
typedef __attribute__((ext_vector_type(4))) float f32x4;
typedef __attribute__((ext_vector_type(16))) float f32x16;
typedef __attribute__((ext_vector_type(2))) unsigned u32x2;
typedef __attribute__((ext_vector_type(4))) unsigned u32x4;

#define B_ 8
#define T_ 340
#define M_ 32
#define H_ 512
#define NH_ 8
#define DH_ 64
#define INFO_ 1020
#define L_ 1084
#define LP_ 1088
#define MROWS 8672
#define MPAD 8704
#define HMLP 2048

__device__ __forceinline__ ushort_t f2bf(float f) {
  unsigned u = __builtin_bit_cast(unsigned, f);
  unsigned r = (u + 0x7fffu + ((u >> 16) & 1u)) >> 16;
  return (ushort_t)r;
}

__device__ __forceinline__ unsigned cvtpk_bf16(float lo, float hi) {
  unsigned r;
  asm volatile("v_cvt_pk_bf16_f32 %0, %1, %2" : "=v"(r) : "v"(lo), "v"(hi));
  return r;
}

__device__ __forceinline__ void gload16(const ushort_t* g, ushort_t* l) {
  __builtin_amdgcn_global_load_lds((const __attribute__((address_space(1))) unsigned*)g,
                                   (__attribute__((address_space(3))) unsigned*)l, 16, 0, 0);
}

// ---------------- zero pads (Q/K l-pads, Vt l-pads, Ob row-pads) ----------------
__global__ __launch_bounds__(256) void zero_pads_kernel(ushort_t* Qb, ushort_t* Kb,
                                                        ushort_t* Vt, ushort_t* Ob) {
  int idx = blockIdx.x * 256 + threadIdx.x;
  if (idx < 16384) {
    int bh = idx >> 8;
    int rest = idx & 255;
    int l = L_ + (rest >> 6);
    int d = rest & 63;
    size_t o = ((size_t)bh * LP_ + l) * DH_ + d;
    Qb[o] = 0;
    Kb[o] = 0;
    Vt[((size_t)bh * DH_ + d) * LP_ + l] = 0;
  } else if (idx < 32768) {
    int j = idx - 16384;
    Ob[(size_t)MROWS * H_ + j] = 0;
  }
}

// ---------------- f32 -> bf16 convert, 8 elems/thread ----------------
__global__ __launch_bounds__(256) void cvt8_kernel(const float* __restrict__ src,
                                                   ushort_t* __restrict__ dst, int n8) {
  int i = blockIdx.x * 256 + threadIdx.x;
  if (i >= n8) return;
  f32x4 a = ((const f32x4*)src)[2 * i];
  f32x4 b = ((const f32x4*)src)[2 * i + 1];
  u32x4 o;
  o.x = cvtpk_bf16(a[0], a[1]);
  o.y = cvtpk_bf16(a[2], a[3]);
  o.z = cvtpk_bf16(b[0], b[1]);
  o.w = cvtpk_bf16(b[2], b[3]);
  ((u32x4*)dst)[i] = o;
}

// ---------------- Wq/Wk/Wv -> concatenated bf16 [nb][1536][512], 8/thread ----------
__global__ __launch_bounds__(256) void cvtqkv_kernel(const float* __restrict__ q,
                                                     const float* __restrict__ k,
                                                     const float* __restrict__ v,
                                                     ushort_t* __restrict__ dst) {
  int i8 = blockIdx.x * 256 + threadIdx.x;
  if (i8 >= 131072) return;  // 4*512*512/8
  int i = i8 * 8;
  int nb = i >> 18;
  int rem = i & 262143;
  size_t base8 = ((size_t)nb * 786432 + rem) >> 3;
  const float* srcs[3] = {q, k, v};
#pragma unroll
  for (int w = 0; w < 3; w++) {
    f32x4 a = ((const f32x4*)srcs[w])[2 * i8];
    f32x4 b = ((const f32x4*)srcs[w])[2 * i8 + 1];
    u32x4 o;
    o.x = cvtpk_bf16(a[0], a[1]);
    o.y = cvtpk_bf16(a[2], a[3]);
    o.z = cvtpk_bf16(b[0], b[1]);
    o.w = cvtpk_bf16(b[2], b[3]);
    ((u32x4*)dst)[base8 + (size_t)w * 32768] = o;  // 262144/8
  }
}

__global__ __launch_bounds__(256) void biascat_kernel(const float* __restrict__ bq,
                                                      const float* __restrict__ bk,
                                                      const float* __restrict__ bv,
                                                      float* __restrict__ dst) {
  int i = blockIdx.x * 256 + threadIdx.x;
  if (i < 2048) {
    int nb = i >> 9, r = i & 511;
    float* d = dst + nb * 1536;
    d[r] = bq[i];
    d[512 + r] = bk[i];
    d[1024 + r] = bv[i];
  }
}

// ---------------- embedding + initial LN ----------------
__global__ __launch_bounds__(256) void embed_ln_kernel(
    const float* __restrict__ returns, const float* __restrict__ actions,
    const float* __restrict__ t_table, const float* __restrict__ s_table,
    const float* __restrict__ Wr, const float* __restrict__ br,
    const float* __restrict__ Wa, const float* __restrict__ ba,
    const float* __restrict__ g, const float* __restrict__ be,
    const float* __restrict__ read_mem, const float* __restrict__ mem_tok,
    const int* __restrict__ states, const int* __restrict__ timestep,
    float* __restrict__ X, ushort_t* __restrict__ Xb) {
  const int row = blockIdx.x;
  const int tid = threadIdx.x;
  if (row >= MROWS) {
    Xb[(size_t)row * H_ + tid] = 0;
    Xb[(size_t)row * H_ + tid + 256] = 0;
    return;
  }
  const int b = row / L_, l = row - b * L_;
  float v[2];
#pragma unroll
  for (int s2 = 0; s2 < 2; s2++) {
    int hh = tid + s2 * 256;
    float val;
    if (l < M_) {
      val = read_mem[(size_t)l * H_ + hh];
    } else if (l >= M_ + INFO_) {
      val = mem_tok[(size_t)(l - M_ - INFO_) * H_ + hh];
    } else {
      int ii = l - M_;
      int t = ii / 3, c = ii - t * 3;
      int bt = b * T_ + t;
      if (c == 1) {
        val = s_table[(size_t)states[bt] * H_ + hh];
      } else {
        float te = t_table[(size_t)timestep[bt] * H_ + hh];
        val = (c == 0 ? returns[bt] * Wr[hh] + br[hh] : actions[bt] * Wa[hh] + ba[hh]) + te;
      }
    }
    v[s2] = val;
  }
  float sum = v[0] + v[1], sq = v[0] * v[0] + v[1] * v[1];
  __shared__ float sa[4], sb[4];
#pragma unroll
  for (int o = 1; o < 64; o <<= 1) {
    sum += __shfl_xor(sum, o);
    sq += __shfl_xor(sq, o);
  }
  int wv = tid >> 6, lane = tid & 63;
  if (lane == 0) { sa[wv] = sum; sb[wv] = sq; }
  __syncthreads();
  sum = sa[0] + sa[1] + sa[2] + sa[3];
  sq = sb[0] + sb[1] + sb[2] + sb[3];
  float mu = sum * (1.0f / H_);
  float var = sq * (1.0f / H_) - mu * mu;
  float rstd = rsqrtf(var + 1e-5f);
#pragma unroll
  for (int s2 = 0; s2 < 2; s2++) {
    int hh = tid + s2 * 256;
    float y = (v[s2] - mu) * rstd * g[hh] + be[hh];
    X[(size_t)row * H_ + hh] = y;
    Xb[(size_t)row * H_ + hh] = f2bf(y);
  }
}

// ---------------- LN over residual stream (in place) ----------------
__global__ __launch_bounds__(256) void ln_kernel(float* __restrict__ X,
                                                 const float* __restrict__ g,
                                                 const float* __restrict__ be,
                                                 ushort_t* __restrict__ Xb) {
  const int row = blockIdx.x;
  const int tid = threadIdx.x;
  if (row >= MROWS) {
    Xb[(size_t)row * H_ + tid] = 0;
    Xb[(size_t)row * H_ + tid + 256] = 0;
    return;
  }
  float v0 = X[(size_t)row * H_ + tid];
  float v1 = X[(size_t)row * H_ + tid + 256];
  float sum = v0 + v1, sq = v0 * v0 + v1 * v1;
  __shared__ float sa[4], sb[4];
#pragma unroll
  for (int o = 1; o < 64; o <<= 1) {
    sum += __shfl_xor(sum, o);
    sq += __shfl_xor(sq, o);
  }
  int wv = tid >> 6, lane = tid & 63;
  if (lane == 0) { sa[wv] = sum; sb[wv] = sq; }
  __syncthreads();
  sum = sa[0] + sa[1] + sa[2] + sa[3];
  sq = sb[0] + sb[1] + sb[2] + sb[3];
  float mu = sum * (1.0f / H_);
  float var = sq * (1.0f / H_) - mu * mu;
  float rstd = rsqrtf(var + 1e-5f);
  float y0 = (v0 - mu) * rstd * g[tid] + be[tid];
  float y1 = (v1 - mu) * rstd * g[tid + 256] + be[tid + 256];
  X[(size_t)row * H_ + tid] = y0;
  X[(size_t)row * H_ + tid + 256] = y1;
  Xb[(size_t)row * H_ + tid] = f2bf(y0);
  Xb[(size_t)row * H_ + tid + 256] = f2bf(y1);
}

// ---------------- GEMM: BK=64, dbuf LDS, counted vmcnt, XOR swizzle, XCD chunking ----
// MODE 0: fused QKV, N=1536 -> scatter Q(scaled)->(b,h,l,d), K->(b,h,l,d), V->(b,h,d,l)
// MODE 2: f32 o0[m,n] = resid[m,n] + acc + bias
// MODE 3: bf16 o0[m,n] = gelu(acc + bias), N=2048
template <int MODE>
__global__ __launch_bounds__(256, 2) void gemm_kernel(const ushort_t* __restrict__ A,
                                                      const ushort_t* __restrict__ W,
                                                      const float* __restrict__ bias,
                                                      void* __restrict__ o0,
                                                      void* __restrict__ o1,
                                                      void* __restrict__ o2,
                                                      const float* __restrict__ resid,
                                                      int Ntiles, int K) {
  __shared__ ushort_t As[2][8192];
  __shared__ ushort_t Bs[2][8192];
  const int tid = threadIdx.x;
  // chunked XCD mapping: HW sends bid%8 -> XCD; give each XCD a contiguous job
  // range so the 4 bx-jobs sharing an A-panel (bx inner) + B stay in one L2.
  const int job = (blockIdx.x & 7) * (gridDim.x >> 3) + (blockIdx.x >> 3);
  const int bx = job % Ntiles, by = job / Ntiles;
  const int m0 = by * 128, n0 = bx * 128;
  const int lane = tid & 63, wv = tid >> 6;
  const int wr = wv >> 1, wc = wv & 1;
  f32x4 acc[4][4] = {};

  const int srow = lane >> 3;
  const int kg = (lane & 7) ^ srow;
  const ushort_t* Asrc[4];
  const ushort_t* Bsrc[4];
#pragma unroll
  for (int g2 = 0; g2 < 4; g2++) {
    int row = wv * 32 + g2 * 8 + srow;
    Asrc[g2] = A + (size_t)(m0 + row) * K + kg * 8;
    Bsrc[g2] = W + (size_t)(n0 + row) * K + kg * 8;
  }
  ushort_t* ldsA[2] = {&As[0][wv * 2048], &As[1][wv * 2048]};
  ushort_t* ldsB[2] = {&Bs[0][wv * 2048], &Bs[1][wv * 2048]};

  const int NT = K >> 6;

#pragma unroll
  for (int g2 = 0; g2 < 4; g2++) {
    gload16(Asrc[g2], ldsA[0] + g2 * 512);
    gload16(Bsrc[g2], ldsB[0] + g2 * 512);
  }

  const int q = lane >> 4, lr = lane & 15;
  const int s0 = q ^ (lr & 7);
  const int s1 = (4 + q) ^ (lr & 7);

  auto compute_tile = [&](int cur) {
    bf16x8 af[4][2], bfr[4][2];
#pragma unroll
    for (int mi = 0; mi < 4; mi++) {
      const ushort_t* rp = &As[cur][(wr * 64 + mi * 16 + lr) * 64];
      af[mi][0] = *(const bf16x8*)(rp + s0 * 8);
      af[mi][1] = *(const bf16x8*)(rp + s1 * 8);
    }
#pragma unroll
    for (int ni = 0; ni < 4; ni++) {
      const ushort_t* rp = &Bs[cur][(wc * 64 + ni * 16 + lr) * 64];
      bfr[ni][0] = *(const bf16x8*)(rp + s0 * 8);
      bfr[ni][1] = *(const bf16x8*)(rp + s1 * 8);
    }
#pragma unroll
    for (int kc = 0; kc < 2; kc++)
#pragma unroll
      for (int mi = 0; mi < 4; mi++)
#pragma unroll
        for (int ni = 0; ni < 4; ni++)
          acc[mi][ni] =
              __builtin_amdgcn_mfma_f32_16x16x32_bf16(af[mi][kc], bfr[ni][kc], acc[mi][ni], 0, 0, 0);
  };

  for (int kt = 0; kt < NT - 1; kt++) {
    const int cur = kt & 1, nxt = cur ^ 1;
    const int k0n = (kt + 1) << 6;
#pragma unroll
    for (int g2 = 0; g2 < 4; g2++) {
      gload16(Asrc[g2] + k0n, ldsA[nxt] + g2 * 512);
      gload16(Bsrc[g2] + k0n, ldsB[nxt] + g2 * 512);
    }
    asm volatile("s_waitcnt vmcnt(8)" ::: "memory");
    __builtin_amdgcn_s_barrier();
    asm volatile("" ::: "memory");
    compute_tile(cur);
    asm volatile("" ::: "memory");
    __builtin_amdgcn_s_barrier();
  }
  {
    asm volatile("s_waitcnt vmcnt(0)" ::: "memory");
    __builtin_amdgcn_s_barrier();
    asm volatile("" ::: "memory");
    compute_tile((NT - 1) & 1);
  }

#pragma unroll
  for (int mi = 0; mi < 4; mi++) {
#pragma unroll
    for (int ni = 0; ni < 4; ni++) {
#pragma unroll
      for (int r = 0; r < 4; r++) {
        int m = m0 + wr * 64 + mi * 16 + ((lane >> 4) << 2) + r;
        int n = n0 + wc * 64 + ni * 16 + (lane & 15);
        float val = acc[mi][ni][r] + bias[n];
        if (MODE == 0) {
          if (m < MROWS) {
            int b = m / L_;
            int l = m - b * L_;
            int which = n >> 9, nn = n & 511;
            int hh = nn >> 6, d = nn & 63;
            if (which == 0) {
              val *= 0.18033688011112043f;  // fold 0.125*log2(e) into Q
              ((ushort_t*)o0)[(((size_t)(b * NH_ + hh)) * LP_ + l) * DH_ + d] = f2bf(val);
            } else if (which == 1)
              ((ushort_t*)o1)[(((size_t)(b * NH_ + hh)) * LP_ + l) * DH_ + d] = f2bf(val);
            else
              ((ushort_t*)o2)[(((size_t)(b * NH_ + hh)) * DH_ + d) * LP_ + l] = f2bf(val);
          }
        } else if (MODE == 2) {
          if (m < MROWS) {
            size_t off = (size_t)m * H_ + n;
            ((float*)o0)[off] = resid[off] + val;
          }
        } else {
          float ge = 0.5f * val * (1.0f + erff(val * 0.70710678f));
          ((ushort_t*)o0)[(size_t)m * HMLP + n] = f2bf(ge);
        }
      }
    }
  }
}

// ---------------- flash attention v3: one 32-row tile per wave, schedule-balanced ----
__global__ __launch_bounds__(256) void attn_kernel(const ushort_t* __restrict__ Qb,
                                                   const ushort_t* __restrict__ Kb,
                                                   const ushort_t* __restrict__ Vt,
                                                   ushort_t* __restrict__ Ob) {
  const int tid = threadIdx.x;
  const int lane = tid & 63, wv = tid >> 6;
  const int xcd = blockIdx.x & 7, jb = blockIdx.x >> 3;  // jb 0..67
  const int t = 33 - (jb >> 1);
  const int bh = (((xcd << 1) | (jb & 1)) << 2) + wv;  // 0..63
  const int b = bh >> 3, h = bh & 7;
  const int qb = t * 32;
  const int lq = lane & 31, hi = lane >> 5;

  const ushort_t* Qp = Qb + (size_t)bh * LP_ * DH_;
  const ushort_t* Kp = Kb + (size_t)bh * LP_ * DH_;
  const ushort_t* Vp = Vt + (size_t)bh * DH_ * LP_;

  bf16x8 qf[4];
#pragma unroll
  for (int dc = 0; dc < 4; dc++)
    qf[dc] = *(const bf16x8*)(Qp + (size_t)(qb + lq) * DH_ + dc * 16 + hi * 8);

  f32x16 o0 = {}, o1 = {};
  float lsum = 0.f;
  const int i = qb + lq;
  const int nk = (t == 33) ? 34 : (t + 1);
  const int cmask = (t == 0) ? -1 : (nk - 1);

  auto loadKV = [&](int c, bf16x8(&kf)[4], bf16x8(&vf)[4]) {
    const int j = c * 32;
#pragma unroll
    for (int dc = 0; dc < 4; dc++)
      kf[dc] = *(const bf16x8*)(Kp + (size_t)(j + lq) * DH_ + dc * 16 + hi * 8);
#pragma unroll
    for (int f = 0; f < 4; f++) {
      int dt = f >> 1, cc = f & 1;
      vf[f] = *(const bf16x8*)(Vp + (size_t)(dt * 32 + lq) * LP_ + j + cc * 16 + hi * 8);
    }
  };

  auto step = [&](int c, const bf16x8(&kf)[4], const bf16x8(&vf)[4]) {
    f32x16 s = {};
#pragma unroll
    for (int dc = 0; dc < 4; dc++)
      s = __builtin_amdgcn_mfma_f32_32x32x16_bf16(kf[dc], qf[dc], s, 0, 0, 0);
    float p[16];
    if (c == cmask) {
#pragma unroll
      for (int r = 0; r < 16; r++) {
        int jcol = c * 32 + (r & 3) + 8 * (r >> 2) + 4 * hi;
        bool ok = (jcol < L_) && ((jcol < M_) || (i >= M_ + INFO_) || (jcol <= i));
        p[r] = ok ? __builtin_amdgcn_exp2f(s[r]) : 0.f;
      }
    } else {
#pragma unroll
      for (int r = 0; r < 16; r++) p[r] = __builtin_amdgcn_exp2f(s[r]);
    }
    float u0 = (p[0] + p[1]) + (p[2] + p[3]);
    float u1 = (p[4] + p[5]) + (p[6] + p[7]);
    float u2 = (p[8] + p[9]) + (p[10] + p[11]);
    float u3 = (p[12] + p[13]) + (p[14] + p[15]);
    lsum += (u0 + u1) + (u2 + u3);
    bf16x8 pf[2];
#pragma unroll
    for (int cc = 0; cc < 2; cc++) {
      unsigned A01 = cvtpk_bf16(p[8 * cc + 0], p[8 * cc + 1]);
      unsigned A23 = cvtpk_bf16(p[8 * cc + 2], p[8 * cc + 3]);
      unsigned B45 = cvtpk_bf16(p[8 * cc + 4], p[8 * cc + 5]);
      unsigned B67 = cvtpk_bf16(p[8 * cc + 6], p[8 * cc + 7]);
      u32x2 r0 = __builtin_amdgcn_permlane32_swap(A01, B45, false, false);
      u32x2 r1 = __builtin_amdgcn_permlane32_swap(A23, B67, false, false);
      u32x4 w = {r0.x, r1.x, r0.y, r1.y};
      pf[cc] = __builtin_bit_cast(bf16x8, w);
    }
    o0 = __builtin_amdgcn_mfma_f32_32x32x16_bf16(vf[0], pf[0], o0, 0, 0, 0);
    o0 = __builtin_amdgcn_mfma_f32_32x32x16_bf16(vf[1], pf[1], o0, 0, 0, 0);
    o1 = __builtin_amdgcn_mfma_f32_32x32x16_bf16(vf[2], pf[0], o1, 0, 0, 0);
    o1 = __builtin_amdgcn_mfma_f32_32x32x16_bf16(vf[3], pf[1], o1, 0, 0, 0);
  };

  bf16x8 kfA[4], vfA[4], kfB[4], vfB[4];
  loadKV(0, kfA, vfA);
  for (int c = 0; c < nk; c += 2) {
    if (c + 1 < nk) loadKV(c + 1, kfB, vfB);
    step(c, kfA, vfA);
    if (c + 1 >= nk) break;
    if (c + 2 < nk) loadKV(c + 2, kfA, vfA);
    step(c + 1, kfB, vfB);
  }

  {
    u32x2 tt = __builtin_amdgcn_permlane32_swap(__builtin_bit_cast(unsigned, lsum),
                                                __builtin_bit_cast(unsigned, lsum), false, false);
    lsum = __builtin_bit_cast(float, tt.x) + __builtin_bit_cast(float, tt.y);
  }

  if (i < L_) {
    const float inv = 1.0f / lsum;
    ushort_t* orow = Ob + ((size_t)(b * L_ + i)) * H_ + h * DH_;
#pragma unroll
    for (int dt = 0; dt < 2; dt++) {
#pragma unroll
      for (int q2 = 0; q2 < 4; q2++) {
        float v0 = (dt ? o1[4 * q2 + 0] : o0[4 * q2 + 0]) * inv;
        float v1 = (dt ? o1[4 * q2 + 1] : o0[4 * q2 + 1]) * inv;
        float v2 = (dt ? o1[4 * q2 + 2] : o0[4 * q2 + 2]) * inv;
        float v3 = (dt ? o1[4 * q2 + 3] : o0[4 * q2 + 3]) * inv;
        int dbase = dt * 32 + 8 * q2 + 4 * hi;
        *(unsigned*)(orow + dbase) = cvtpk_bf16(v0, v1);
        *(unsigned*)(orow + dbase + 2) = cvtpk_bf16(v2, v3);
      }
    }
  }
}

// ---------------- heads ----------------
__global__ __launch_bounds__(64) void logits_kernel(const float* __restrict__ X,
                                                    const float* __restrict__ Wp,
                                                    const float* __restrict__ bp,
                                                    float* __restrict__ out) {
  const int bt = blockIdx.x;
  const int b = bt / T_, t = bt - b * T_;
  const int lane = threadIdx.x;
  const float* xr = X + ((size_t)(b * L_ + M_ + 3 * t + 1)) * H_ + lane * 8;
  float x0[8];
#pragma unroll
  for (int ii = 0; ii < 8; ii++) x0[ii] = xr[ii];
#pragma unroll
  for (int a = 0; a < 4; a++) {
    const float* wr2 = Wp + (size_t)a * H_ + lane * 8;
    float p = 0.f;
#pragma unroll
    for (int ii = 0; ii < 8; ii++) p += x0[ii] * wr2[ii];
#pragma unroll
    for (int o = 1; o < 64; o <<= 1) p += __shfl_xor(p, o);
    if (lane == 0) out[(size_t)bt * 4 + a] = p + bp[a];
  }
}

__global__ __launch_bounds__(256) void memout_kernel(const float* __restrict__ X,
                                                     float* __restrict__ out) {
  int idx = blockIdx.x * 256 + threadIdx.x;
  if (idx < B_ * M_ * H_) {
    int b = idx >> 14;
    int rest = idx & 16383;
    int r = rest >> 9;
    int hh = rest & 511;
    out[idx] = X[((size_t)(b * L_ + M_ + INFO_ + r)) * H_ + hh];
  }
}

// ---------------- launcher ----------------
extern "C" void kernel_launch(void* const* d_in, const int* in_sizes, int n_in, void* d_out,
                              int out_size, void* d_ws, size_t ws_size, hipStream_t stream) {
  const float* returns = (const float*)d_in[0];
  const float* actions = (const float*)d_in[1];
  const float* t_table = (const float*)d_in[2];
  const float* s_table = (const float*)d_in[3];
  const float* Wr = (const float*)d_in[4];
  const float* br = (const float*)d_in[5];
  const float* Wa = (const float*)d_in[6];
  const float* ba = (const float*)d_in[7];
  const float* ln_e_g = (const float*)d_in[8];
  const float* ln_e_b = (const float*)d_in[9];
  const float* read_mem = (const float*)d_in[10];
  const float* mem_tok = (const float*)d_in[11];
  const float* Wq = (const float*)d_in[12];
  const float* bq = (const float*)d_in[13];
  const float* Wk = (const float*)d_in[14];
  const float* bk = (const float*)d_in[15];
  const float* Wv = (const float*)d_in[16];
  const float* bv = (const float*)d_in[17];
  const float* Wo = (const float*)d_in[18];
  const float* bo = (const float*)d_in[19];
  const float* W1 = (const float*)d_in[20];
  const float* b1 = (const float*)d_in[21];
  const float* W2 = (const float*)d_in[22];
  const float* b2 = (const float*)d_in[23];
  const float* g1 = (const float*)d_in[24];
  const float* be1 = (const float*)d_in[25];
  const float* g2 = (const float*)d_in[26];
  const float* be2 = (const float*)d_in[27];
  const float* Wp = (const float*)d_in[28];
  const float* bp = (const float*)d_in[29];
  const int* states = (const int*)d_in[30];
  const int* timestep = (const int*)d_in[31];

  char* ws = (char*)d_ws;
  size_t off = 0;
  auto alloc = [&](size_t bytes) -> char* {
    char* p = ws + off;
    off += (bytes + 255) & ~(size_t)255;
    return p;
  };
  float* X = (float*)alloc((size_t)MPAD * H_ * 4);
  ushort_t* Xb = (ushort_t*)alloc((size_t)MPAD * H_ * 2);
  ushort_t* Qb = (ushort_t*)alloc((size_t)B_ * NH_ * LP_ * DH_ * 2);
  ushort_t* Kb2 = (ushort_t*)alloc((size_t)B_ * NH_ * LP_ * DH_ * 2);
  ushort_t* Vt = (ushort_t*)alloc((size_t)B_ * NH_ * DH_ * LP_ * 2);
  ushort_t* Ob = (ushort_t*)alloc((size_t)MPAD * H_ * 2);
  ushort_t* Hm = (ushort_t*)alloc((size_t)MPAD * HMLP * 2);
  ushort_t* Wqkvb = (ushort_t*)alloc((size_t)4 * 1536 * 512 * 2);
  ushort_t* Wob = (ushort_t*)alloc((size_t)4 * 512 * 512 * 2);
  ushort_t* W1b = (ushort_t*)alloc((size_t)4 * 2048 * 512 * 2);
  ushort_t* W2b = (ushort_t*)alloc((size_t)4 * 512 * 2048 * 2);
  float* biascat = (float*)alloc((size_t)4 * 1536 * 4);

  zero_pads_kernel<<<128, 256, 0, stream>>>(Qb, Kb2, Vt, Ob);
  cvtqkv_kernel<<<512, 256, 0, stream>>>(Wq, Wk, Wv, Wqkvb);
  biascat_kernel<<<8, 256, 0, stream>>>(bq, bk, bv, biascat);
  cvt8_kernel<<<512, 256, 0, stream>>>(Wo, Wob, 4 * 512 * 512 / 8);
  cvt8_kernel<<<2048, 256, 0, stream>>>(W1, W1b, 4 * 2048 * 512 / 8);
  cvt8_kernel<<<2048, 256, 0, stream>>>(W2, W2b, 4 * 512 * 2048 / 8);

  embed_ln_kernel<<<MPAD, 256, 0, stream>>>(returns, actions, t_table, s_table, Wr, br, Wa,
                                            ba, ln_e_g, ln_e_b, read_mem, mem_tok, states,
                                            timestep, X, Xb);

  for (int nb = 0; nb < 4; ++nb) {
    const size_t wo512 = (size_t)nb * 512 * 512;
    const size_t woqkv = (size_t)nb * 1536 * 512;
    const size_t wo1 = (size_t)nb * 2048 * 512;
    gemm_kernel<0><<<68 * 12, 256, 0, stream>>>(Xb, Wqkvb + woqkv, biascat + nb * 1536, Qb,
                                                Kb2, Vt, nullptr, 12, 512);
    attn_kernel<<<544, 256, 0, stream>>>(Qb, Kb2, Vt, Ob);
    gemm_kernel<2><<<68 * 4, 256, 0, stream>>>(Ob, Wob + wo512, bo + nb * 512, X, nullptr,
                                               nullptr, X, 4, 512);
    ln_kernel<<<MPAD, 256, 0, stream>>>(X, g1 + nb * 512, be1 + nb * 512, Xb);
    gemm_kernel<3><<<68 * 16, 256, 0, stream>>>(Xb, W1b + wo1, b1 + nb * 2048, Hm, nullptr,
                                                nullptr, nullptr, 16, 512);
    gemm_kernel<2><<<68 * 4, 256, 0, stream>>>(Hm, W2b + wo1, b2 + nb * 512, X, nullptr,
                                               nullptr, X, 4, 2048);
    ln_kernel<<<MPAD, 256, 0, stream>>>(X, g2 + nb * 512, be2 + nb * 512, Xb);
  }

  logits_kernel<<<B_ * T_, 64, 0, stream>>>(X, Wp, bp, (float*)d_out);
  memout_kernel<<<512, 256, 0, stream>>>(X, (float*)d_out + (size_t)B_ * T_ * 4);
}

// Round 7
// 913.693 us; speedup vs baseline: 1.1643x; 1.1643x over previous
//
#include <hip/hip_runtime.h>
#include <hip/hip_bf16.h>

typedef unsigned short ushort_t;
typedef __attribute__((ext_vector_type(8))) __bf16 bf16x8;
typedef __attribute__((ext_vector_type(4))) float f32x4;
typedef __attribute__((ext_vector_type(16))) float f32x16;
typedef __attribute__((ext_vector_type(2))) unsigned u32x2;
typedef __attribute__((ext_vector_type(4))) unsigned u32x4;

#define B_ 8
#define T_ 340
#define M_ 32
#define H_ 512
#define NH_ 8
#define DH_ 64
#define INFO_ 1020
#define L_ 1084
#define LP_ 1088
#define MROWS 8672
#define MPAD 8704
#define HMLP 2048

__device__ __forceinline__ ushort_t f2bf(float f) {
  unsigned u = __builtin_bit_cast(unsigned, f);
  unsigned r = (u + 0x7fffu + ((u >> 16) & 1u)) >> 16;
  return (ushort_t)r;
}

__device__ __forceinline__ unsigned cvtpk_bf16(float lo, float hi) {
  unsigned r;
  asm volatile("v_cvt_pk_bf16_f32 %0, %1, %2" : "=v"(r) : "v"(lo), "v"(hi));
  return r;
}

__device__ __forceinline__ void gload16(const ushort_t* g, ushort_t* l) {
  __builtin_amdgcn_global_load_lds((const __attribute__((address_space(1))) unsigned*)g,
                                   (__attribute__((address_space(3))) unsigned*)l, 16, 0, 0);
}

// ---------------- zero pads (Q/K l-pads, Vt l-pads, Ob row-pads) ----------------
__global__ __launch_bounds__(256) void zero_pads_kernel(ushort_t* Qb, ushort_t* Kb,
                                                        ushort_t* Vt, ushort_t* Ob) {
  int idx = blockIdx.x * 256 + threadIdx.x;
  if (idx < 16384) {
    int bh = idx >> 8;
    int rest = idx & 255;
    int l = L_ + (rest >> 6);
    int d = rest & 63;
    size_t o = ((size_t)bh * LP_ + l) * DH_ + d;
    Qb[o] = 0;
    Kb[o] = 0;
    Vt[((size_t)bh * DH_ + d) * LP_ + l] = 0;
  } else if (idx < 32768) {
    int j = idx - 16384;
    Ob[(size_t)MROWS * H_ + j] = 0;
  }
}

// ---------------- f32 -> bf16 convert, 8 elems/thread ----------------
__global__ __launch_bounds__(256) void cvt8_kernel(const float* __restrict__ src,
                                                   ushort_t* __restrict__ dst, int n8) {
  int i = blockIdx.x * 256 + threadIdx.x;
  if (i >= n8) return;
  f32x4 a = ((const f32x4*)src)[2 * i];
  f32x4 b = ((const f32x4*)src)[2 * i + 1];
  u32x4 o;
  o.x = cvtpk_bf16(a[0], a[1]);
  o.y = cvtpk_bf16(a[2], a[3]);
  o.z = cvtpk_bf16(b[0], b[1]);
  o.w = cvtpk_bf16(b[2], b[3]);
  ((u32x4*)dst)[i] = o;
}

// ---------------- Wq/Wk/Wv -> concatenated bf16 [nb][1536][512], 8/thread ----------
__global__ __launch_bounds__(256) void cvtqkv_kernel(const float* __restrict__ q,
                                                     const float* __restrict__ k,
                                                     const float* __restrict__ v,
                                                     ushort_t* __restrict__ dst) {
  int i8 = blockIdx.x * 256 + threadIdx.x;
  if (i8 >= 131072) return;  // 4*512*512/8
  int i = i8 * 8;
  int nb = i >> 18;
  int rem = i & 262143;
  size_t base8 = ((size_t)nb * 786432 + rem) >> 3;
  const float* srcs[3] = {q, k, v};
#pragma unroll
  for (int w = 0; w < 3; w++) {
    f32x4 a = ((const f32x4*)srcs[w])[2 * i8];
    f32x4 b = ((const f32x4*)srcs[w])[2 * i8 + 1];
    u32x4 o;
    o.x = cvtpk_bf16(a[0], a[1]);
    o.y = cvtpk_bf16(a[2], a[3]);
    o.z = cvtpk_bf16(b[0], b[1]);
    o.w = cvtpk_bf16(b[2], b[3]);
    ((u32x4*)dst)[base8 + (size_t)w * 32768] = o;  // 262144/8
  }
}

__global__ __launch_bounds__(256) void biascat_kernel(const float* __restrict__ bq,
                                                      const float* __restrict__ bk,
                                                      const float* __restrict__ bv,
                                                      float* __restrict__ dst) {
  int i = blockIdx.x * 256 + threadIdx.x;
  if (i < 2048) {
    int nb = i >> 9, r = i & 511;
    float* d = dst + nb * 1536;
    d[r] = bq[i];
    d[512 + r] = bk[i];
    d[1024 + r] = bv[i];
  }
}

// ---------------- embedding + initial LN ----------------
__global__ __launch_bounds__(256) void embed_ln_kernel(
    const float* __restrict__ returns, const float* __restrict__ actions,
    const float* __restrict__ t_table, const float* __restrict__ s_table,
    const float* __restrict__ Wr, const float* __restrict__ br,
    const float* __restrict__ Wa, const float* __restrict__ ba,
    const float* __restrict__ g, const float* __restrict__ be,
    const float* __restrict__ read_mem, const float* __restrict__ mem_tok,
    const int* __restrict__ states, const int* __restrict__ timestep,
    float* __restrict__ X, ushort_t* __restrict__ Xb) {
  const int row = blockIdx.x;
  const int tid = threadIdx.x;
  if (row >= MROWS) {
    Xb[(size_t)row * H_ + tid] = 0;
    Xb[(size_t)row * H_ + tid + 256] = 0;
    return;
  }
  const int b = row / L_, l = row - b * L_;
  float v[2];
#pragma unroll
  for (int s2 = 0; s2 < 2; s2++) {
    int hh = tid + s2 * 256;
    float val;
    if (l < M_) {
      val = read_mem[(size_t)l * H_ + hh];
    } else if (l >= M_ + INFO_) {
      val = mem_tok[(size_t)(l - M_ - INFO_) * H_ + hh];
    } else {
      int ii = l - M_;
      int t = ii / 3, c = ii - t * 3;
      int bt = b * T_ + t;
      if (c == 1) {
        val = s_table[(size_t)states[bt] * H_ + hh];
      } else {
        float te = t_table[(size_t)timestep[bt] * H_ + hh];
        val = (c == 0 ? returns[bt] * Wr[hh] + br[hh] : actions[bt] * Wa[hh] + ba[hh]) + te;
      }
    }
    v[s2] = val;
  }
  float sum = v[0] + v[1], sq = v[0] * v[0] + v[1] * v[1];
  __shared__ float sa[4], sb[4];
#pragma unroll
  for (int o = 1; o < 64; o <<= 1) {
    sum += __shfl_xor(sum, o);
    sq += __shfl_xor(sq, o);
  }
  int wv = tid >> 6, lane = tid & 63;
  if (lane == 0) { sa[wv] = sum; sb[wv] = sq; }
  __syncthreads();
  sum = sa[0] + sa[1] + sa[2] + sa[3];
  sq = sb[0] + sb[1] + sb[2] + sb[3];
  float mu = sum * (1.0f / H_);
  float var = sq * (1.0f / H_) - mu * mu;
  float rstd = rsqrtf(var + 1e-5f);
#pragma unroll
  for (int s2 = 0; s2 < 2; s2++) {
    int hh = tid + s2 * 256;
    float y = (v[s2] - mu) * rstd * g[hh] + be[hh];
    X[(size_t)row * H_ + hh] = y;
    Xb[(size_t)row * H_ + hh] = f2bf(y);
  }
}

// ---------------- LN over residual stream (in place) ----------------
__global__ __launch_bounds__(256) void ln_kernel(float* __restrict__ X,
                                                 const float* __restrict__ g,
                                                 const float* __restrict__ be,
                                                 ushort_t* __restrict__ Xb) {
  const int row = blockIdx.x;
  const int tid = threadIdx.x;
  if (row >= MROWS) {
    Xb[(size_t)row * H_ + tid] = 0;
    Xb[(size_t)row * H_ + tid + 256] = 0;
    return;
  }
  float v0 = X[(size_t)row * H_ + tid];
  float v1 = X[(size_t)row * H_ + tid + 256];
  float sum = v0 + v1, sq = v0 * v0 + v1 * v1;
  __shared__ float sa[4], sb[4];
#pragma unroll
  for (int o = 1; o < 64; o <<= 1) {
    sum += __shfl_xor(sum, o);
    sq += __shfl_xor(sq, o);
  }
  int wv = tid >> 6, lane = tid & 63;
  if (lane == 0) { sa[wv] = sum; sb[wv] = sq; }
  __syncthreads();
  sum = sa[0] + sa[1] + sa[2] + sa[3];
  sq = sb[0] + sb[1] + sb[2] + sb[3];
  float mu = sum * (1.0f / H_);
  float var = sq * (1.0f / H_) - mu * mu;
  float rstd = rsqrtf(var + 1e-5f);
  float y0 = (v0 - mu) * rstd * g[tid] + be[tid];
  float y1 = (v1 - mu) * rstd * g[tid + 256] + be[tid + 256];
  X[(size_t)row * H_ + tid] = y0;
  X[(size_t)row * H_ + tid + 256] = y1;
  Xb[(size_t)row * H_ + tid] = f2bf(y0);
  Xb[(size_t)row * H_ + tid + 256] = f2bf(y1);
}

// ---------------- GEMM: 128x64 tile, BK=64, dbuf LDS (48KB -> 3 blocks/CU), ---------
// counted vmcnt(6), XOR swizzle, chunked XCD mapping.
// MODE 0: fused QKV, N=1536 -> scatter Q(scaled)->(b,h,l,d), K->(b,h,l,d), V->(b,h,d,l)
// MODE 2: f32 o0[m,n] = resid[m,n] + acc + bias
// MODE 3: bf16 o0[m,n] = gelu(acc + bias), N=2048
template <int MODE>
__global__ __launch_bounds__(256, 3) void gemm_kernel(const ushort_t* __restrict__ A,
                                                      const ushort_t* __restrict__ W,
                                                      const float* __restrict__ bias,
                                                      void* __restrict__ o0,
                                                      void* __restrict__ o1,
                                                      void* __restrict__ o2,
                                                      const float* __restrict__ resid,
                                                      int Ntiles, int K) {
  __shared__ ushort_t As[2][8192];  // 128 rows x 64 (x2B)
  __shared__ ushort_t Bs[2][4096];  // 64 rows x 64
  const int tid = threadIdx.x;
  const int job = (blockIdx.x & 7) * (gridDim.x >> 3) + (blockIdx.x >> 3);
  const int bx = job % Ntiles, by = job / Ntiles;
  const int m0 = by * 128, n0 = bx * 64;
  const int lane = tid & 63, wv = tid >> 6;
  const int wr = wv >> 1, wc = wv & 1;
  f32x4 acc[4][2] = {};

  const int srow = lane >> 3;
  const int kg = (lane & 7) ^ srow;
  const ushort_t* Asrc[4];
  const ushort_t* Bsrc[2];
#pragma unroll
  for (int g2 = 0; g2 < 4; g2++) {
    int row = wv * 32 + g2 * 8 + srow;
    Asrc[g2] = A + (size_t)(m0 + row) * K + kg * 8;
  }
#pragma unroll
  for (int g2 = 0; g2 < 2; g2++) {
    int row = wv * 16 + g2 * 8 + srow;
    Bsrc[g2] = W + (size_t)(n0 + row) * K + kg * 8;
  }
  ushort_t* ldsA[2] = {&As[0][wv * 2048], &As[1][wv * 2048]};
  ushort_t* ldsB[2] = {&Bs[0][wv * 1024], &Bs[1][wv * 1024]};

  const int NT = K >> 6;

#pragma unroll
  for (int g2 = 0; g2 < 4; g2++) gload16(Asrc[g2], ldsA[0] + g2 * 512);
#pragma unroll
  for (int g2 = 0; g2 < 2; g2++) gload16(Bsrc[g2], ldsB[0] + g2 * 512);

  const int q = lane >> 4, lr = lane & 15;
  const int s0 = q ^ (lr & 7);
  const int s1 = (4 + q) ^ (lr & 7);

  auto compute_tile = [&](int cur) {
    bf16x8 af[4][2], bfr[2][2];
#pragma unroll
    for (int mi = 0; mi < 4; mi++) {
      const ushort_t* rp = &As[cur][(wr * 64 + mi * 16 + lr) * 64];
      af[mi][0] = *(const bf16x8*)(rp + s0 * 8);
      af[mi][1] = *(const bf16x8*)(rp + s1 * 8);
    }
#pragma unroll
    for (int ni = 0; ni < 2; ni++) {
      const ushort_t* rp = &Bs[cur][(wc * 32 + ni * 16 + lr) * 64];
      bfr[ni][0] = *(const bf16x8*)(rp + s0 * 8);
      bfr[ni][1] = *(const bf16x8*)(rp + s1 * 8);
    }
#pragma unroll
    for (int kc = 0; kc < 2; kc++)
#pragma unroll
      for (int mi = 0; mi < 4; mi++)
#pragma unroll
        for (int ni = 0; ni < 2; ni++)
          acc[mi][ni] =
              __builtin_amdgcn_mfma_f32_16x16x32_bf16(af[mi][kc], bfr[ni][kc], acc[mi][ni], 0, 0, 0);
  };

  for (int kt = 0; kt < NT - 1; kt++) {
    const int cur = kt & 1, nxt = cur ^ 1;
    const int k0n = (kt + 1) << 6;
#pragma unroll
    for (int g2 = 0; g2 < 4; g2++) gload16(Asrc[g2] + k0n, ldsA[nxt] + g2 * 512);
#pragma unroll
    for (int g2 = 0; g2 < 2; g2++) gload16(Bsrc[g2] + k0n, ldsB[nxt] + g2 * 512);
    // wait only for CURRENT tile's 6 loads; next tile's 6 stay in flight
    asm volatile("s_waitcnt vmcnt(6)" ::: "memory");
    __builtin_amdgcn_s_barrier();
    asm volatile("" ::: "memory");
    compute_tile(cur);
    asm volatile("" ::: "memory");
    __builtin_amdgcn_s_barrier();
  }
  {
    asm volatile("s_waitcnt vmcnt(0)" ::: "memory");
    __builtin_amdgcn_s_barrier();
    asm volatile("" ::: "memory");
    compute_tile((NT - 1) & 1);
  }

#pragma unroll
  for (int mi = 0; mi < 4; mi++) {
#pragma unroll
    for (int ni = 0; ni < 2; ni++) {
#pragma unroll
      for (int r = 0; r < 4; r++) {
        int m = m0 + wr * 64 + mi * 16 + ((lane >> 4) << 2) + r;
        int n = n0 + wc * 32 + ni * 16 + (lane & 15);
        float val = acc[mi][ni][r] + bias[n];
        if (MODE == 0) {
          if (m < MROWS) {
            int b = m / L_;
            int l = m - b * L_;
            int which = n >> 9, nn = n & 511;
            int hh = nn >> 6, d = nn & 63;
            if (which == 0) {
              val *= 0.18033688011112043f;  // fold 0.125*log2(e) into Q
              ((ushort_t*)o0)[(((size_t)(b * NH_ + hh)) * LP_ + l) * DH_ + d] = f2bf(val);
            } else if (which == 1)
              ((ushort_t*)o1)[(((size_t)(b * NH_ + hh)) * LP_ + l) * DH_ + d] = f2bf(val);
            else
              ((ushort_t*)o2)[(((size_t)(b * NH_ + hh)) * DH_ + d) * LP_ + l] = f2bf(val);
          }
        } else if (MODE == 2) {
          if (m < MROWS) {
            size_t off = (size_t)m * H_ + n;
            ((float*)o0)[off] = resid[off] + val;
          }
        } else {
          float ge = 0.5f * val * (1.0f + erff(val * 0.70710678f));
          ((ushort_t*)o0)[(size_t)m * HMLP + n] = f2bf(ge);
        }
      }
    }
  }
}

// ---------------- flash attention v3: one 32-row tile per wave, schedule-balanced ----
__global__ __launch_bounds__(256) void attn_kernel(const ushort_t* __restrict__ Qb,
                                                   const ushort_t* __restrict__ Kb,
                                                   const ushort_t* __restrict__ Vt,
                                                   ushort_t* __restrict__ Ob) {
  const int tid = threadIdx.x;
  const int lane = tid & 63, wv = tid >> 6;
  const int xcd = blockIdx.x & 7, jb = blockIdx.x >> 3;  // jb 0..67
  const int t = 33 - (jb >> 1);
  const int bh = (((xcd << 1) | (jb & 1)) << 2) + wv;  // 0..63
  const int b = bh >> 3, h = bh & 7;
  const int qb = t * 32;
  const int lq = lane & 31, hi = lane >> 5;

  const ushort_t* Qp = Qb + (size_t)bh * LP_ * DH_;
  const ushort_t* Kp = Kb + (size_t)bh * LP_ * DH_;
  const ushort_t* Vp = Vt + (size_t)bh * DH_ * LP_;

  bf16x8 qf[4];
#pragma unroll
  for (int dc = 0; dc < 4; dc++)
    qf[dc] = *(const bf16x8*)(Qp + (size_t)(qb + lq) * DH_ + dc * 16 + hi * 8);

  f32x16 o0 = {}, o1 = {};
  float lsum = 0.f;
  const int i = qb + lq;
  const int nk = (t == 33) ? 34 : (t + 1);
  const int cmask = (t == 0) ? -1 : (nk - 1);

  auto loadKV = [&](int c, bf16x8(&kf)[4], bf16x8(&vf)[4]) {
    const int j = c * 32;
#pragma unroll
    for (int dc = 0; dc < 4; dc++)
      kf[dc] = *(const bf16x8*)(Kp + (size_t)(j + lq) * DH_ + dc * 16 + hi * 8);
#pragma unroll
    for (int f = 0; f < 4; f++) {
      int dt = f >> 1, cc = f & 1;
      vf[f] = *(const bf16x8*)(Vp + (size_t)(dt * 32 + lq) * LP_ + j + cc * 16 + hi * 8);
    }
  };

  auto step = [&](int c, const bf16x8(&kf)[4], const bf16x8(&vf)[4]) {
    f32x16 s = {};
#pragma unroll
    for (int dc = 0; dc < 4; dc++)
      s = __builtin_amdgcn_mfma_f32_32x32x16_bf16(kf[dc], qf[dc], s, 0, 0, 0);
    float p[16];
    if (c == cmask) {
#pragma unroll
      for (int r = 0; r < 16; r++) {
        int jcol = c * 32 + (r & 3) + 8 * (r >> 2) + 4 * hi;
        bool ok = (jcol < L_) && ((jcol < M_) || (i >= M_ + INFO_) || (jcol <= i));
        p[r] = ok ? __builtin_amdgcn_exp2f(s[r]) : 0.f;
      }
    } else {
#pragma unroll
      for (int r = 0; r < 16; r++) p[r] = __builtin_amdgcn_exp2f(s[r]);
    }
    float u0 = (p[0] + p[1]) + (p[2] + p[3]);
    float u1 = (p[4] + p[5]) + (p[6] + p[7]);
    float u2 = (p[8] + p[9]) + (p[10] + p[11]);
    float u3 = (p[12] + p[13]) + (p[14] + p[15]);
    lsum += (u0 + u1) + (u2 + u3);
    bf16x8 pf[2];
#pragma unroll
    for (int cc = 0; cc < 2; cc++) {
      unsigned A01 = cvtpk_bf16(p[8 * cc + 0], p[8 * cc + 1]);
      unsigned A23 = cvtpk_bf16(p[8 * cc + 2], p[8 * cc + 3]);
      unsigned B45 = cvtpk_bf16(p[8 * cc + 4], p[8 * cc + 5]);
      unsigned B67 = cvtpk_bf16(p[8 * cc + 6], p[8 * cc + 7]);
      u32x2 r0 = __builtin_amdgcn_permlane32_swap(A01, B45, false, false);
      u32x2 r1 = __builtin_amdgcn_permlane32_swap(A23, B67, false, false);
      u32x4 w = {r0.x, r1.x, r0.y, r1.y};
      pf[cc] = __builtin_bit_cast(bf16x8, w);
    }
    o0 = __builtin_amdgcn_mfma_f32_32x32x16_bf16(vf[0], pf[0], o0, 0, 0, 0);
    o0 = __builtin_amdgcn_mfma_f32_32x32x16_bf16(vf[1], pf[1], o0, 0, 0, 0);
    o1 = __builtin_amdgcn_mfma_f32_32x32x16_bf16(vf[2], pf[0], o1, 0, 0, 0);
    o1 = __builtin_amdgcn_mfma_f32_32x32x16_bf16(vf[3], pf[1], o1, 0, 0, 0);
  };

  bf16x8 kfA[4], vfA[4], kfB[4], vfB[4];
  loadKV(0, kfA, vfA);
  for (int c = 0; c < nk; c += 2) {
    if (c + 1 < nk) loadKV(c + 1, kfB, vfB);
    step(c, kfA, vfA);
    if (c + 1 >= nk) break;
    if (c + 2 < nk) loadKV(c + 2, kfA, vfA);
    step(c + 1, kfB, vfB);
  }

  {
    u32x2 tt = __builtin_amdgcn_permlane32_swap(__builtin_bit_cast(unsigned, lsum),
                                                __builtin_bit_cast(unsigned, lsum), false, false);
    lsum = __builtin_bit_cast(float, tt.x) + __builtin_bit_cast(float, tt.y);
  }

  if (i < L_) {
    const float inv = 1.0f / lsum;
    ushort_t* orow = Ob + ((size_t)(b * L_ + i)) * H_ + h * DH_;
#pragma unroll
    for (int dt = 0; dt < 2; dt++) {
#pragma unroll
      for (int q2 = 0; q2 < 4; q2++) {
        float v0 = (dt ? o1[4 * q2 + 0] : o0[4 * q2 + 0]) * inv;
        float v1 = (dt ? o1[4 * q2 + 1] : o0[4 * q2 + 1]) * inv;
        float v2 = (dt ? o1[4 * q2 + 2] : o0[4 * q2 + 2]) * inv;
        float v3 = (dt ? o1[4 * q2 + 3] : o0[4 * q2 + 3]) * inv;
        int dbase = dt * 32 + 8 * q2 + 4 * hi;
        *(unsigned*)(orow + dbase) = cvtpk_bf16(v0, v1);
        *(unsigned*)(orow + dbase + 2) = cvtpk_bf16(v2, v3);
      }
    }
  }
}

// ---------------- heads ----------------
__global__ __launch_bounds__(64) void logits_kernel(const float* __restrict__ X,
                                                    const float* __restrict__ Wp,
                                                    const float* __restrict__ bp,
                                                    float* __restrict__ out) {
  const int bt = blockIdx.x;
  const int b = bt / T_, t = bt - b * T_;
  const int lane = threadIdx.x;
  const float* xr = X + ((size_t)(b * L_ + M_ + 3 * t + 1)) * H_ + lane * 8;
  float x0[8];
#pragma unroll
  for (int ii = 0; ii < 8; ii++) x0[ii] = xr[ii];
#pragma unroll
  for (int a = 0; a < 4; a++) {
    const float* wr2 = Wp + (size_t)a * H_ + lane * 8;
    float p = 0.f;
#pragma unroll
    for (int ii = 0; ii < 8; ii++) p += x0[ii] * wr2[ii];
#pragma unroll
    for (int o = 1; o < 64; o <<= 1) p += __shfl_xor(p, o);
    if (lane == 0) out[(size_t)bt * 4 + a] = p + bp[a];
  }
}

__global__ __launch_bounds__(256) void memout_kernel(const float* __restrict__ X,
                                                     float* __restrict__ out) {
  int idx = blockIdx.x * 256 + threadIdx.x;
  if (idx < B_ * M_ * H_) {
    int b = idx >> 14;
    int rest = idx & 16383;
    int r = rest >> 9;
    int hh = rest & 511;
    out[idx] = X[((size_t)(b * L_ + M_ + INFO_ + r)) * H_ + hh];
  }
}

// ---------------- launcher ----------------
extern "C" void kernel_launch(void* const* d_in, const int* in_sizes, int n_in, void* d_out,
                              int out_size, void* d_ws, size_t ws_size, hipStream_t stream) {
  const float* returns = (const float*)d_in[0];
  const float* actions = (const float*)d_in[1];
  const float* t_table = (const float*)d_in[2];
  const float* s_table = (const float*)d_in[3];
  const float* Wr = (const float*)d_in[4];
  const float* br = (const float*)d_in[5];
  const float* Wa = (const float*)d_in[6];
  const float* ba = (const float*)d_in[7];
  const float* ln_e_g = (const float*)d_in[8];
  const float* ln_e_b = (const float*)d_in[9];
  const float* read_mem = (const float*)d_in[10];
  const float* mem_tok = (const float*)d_in[11];
  const float* Wq = (const float*)d_in[12];
  const float* bq = (const float*)d_in[13];
  const float* Wk = (const float*)d_in[14];
  const float* bk = (const float*)d_in[15];
  const float* Wv = (const float*)d_in[16];
  const float* bv = (const float*)d_in[17];
  const float* Wo = (const float*)d_in[18];
  const float* bo = (const float*)d_in[19];
  const float* W1 = (const float*)d_in[20];
  const float* b1 = (const float*)d_in[21];
  const float* W2 = (const float*)d_in[22];
  const float* b2 = (const float*)d_in[23];
  const float* g1 = (const float*)d_in[24];
  const float* be1 = (const float*)d_in[25];
  const float* g2 = (const float*)d_in[26];
  const float* be2 = (const float*)d_in[27];
  const float* Wp = (const float*)d_in[28];
  const float* bp = (const float*)d_in[29];
  const int* states = (const int*)d_in[30];
  const int* timestep = (const int*)d_in[31];

  char* ws = (char*)d_ws;
  size_t off = 0;
  auto alloc = [&](size_t bytes) -> char* {
    char* p = ws + off;
    off += (bytes + 255) & ~(size_t)255;
    return p;
  };
  float* X = (float*)alloc((size_t)MPAD * H_ * 4);
  ushort_t* Xb = (ushort_t*)alloc((size_t)MPAD * H_ * 2);
  ushort_t* Qb = (ushort_t*)alloc((size_t)B_ * NH_ * LP_ * DH_ * 2);
  ushort_t* Kb2 = (ushort_t*)alloc((size_t)B_ * NH_ * LP_ * DH_ * 2);
  ushort_t* Vt = (ushort_t*)alloc((size_t)B_ * NH_ * DH_ * LP_ * 2);
  ushort_t* Ob = (ushort_t*)alloc((size_t)MPAD * H_ * 2);
  ushort_t* Hm = (ushort_t*)alloc((size_t)MPAD * HMLP * 2);
  ushort_t* Wqkvb = (ushort_t*)alloc((size_t)4 * 1536 * 512 * 2);
  ushort_t* Wob = (ushort_t*)alloc((size_t)4 * 512 * 512 * 2);
  ushort_t* W1b = (ushort_t*)alloc((size_t)4 * 2048 * 512 * 2);
  ushort_t* W2b = (ushort_t*)alloc((size_t)4 * 512 * 2048 * 2);
  float* biascat = (float*)alloc((size_t)4 * 1536 * 4);

  zero_pads_kernel<<<128, 256, 0, stream>>>(Qb, Kb2, Vt, Ob);
  cvtqkv_kernel<<<512, 256, 0, stream>>>(Wq, Wk, Wv, Wqkvb);
  biascat_kernel<<<8, 256, 0, stream>>>(bq, bk, bv, biascat);
  cvt8_kernel<<<512, 256, 0, stream>>>(Wo, Wob, 4 * 512 * 512 / 8);
  cvt8_kernel<<<2048, 256, 0, stream>>>(W1, W1b, 4 * 2048 * 512 / 8);
  cvt8_kernel<<<2048, 256, 0, stream>>>(W2, W2b, 4 * 512 * 2048 / 8);

  embed_ln_kernel<<<MPAD, 256, 0, stream>>>(returns, actions, t_table, s_table, Wr, br, Wa,
                                            ba, ln_e_g, ln_e_b, read_mem, mem_tok, states,
                                            timestep, X, Xb);

  for (int nb = 0; nb < 4; ++nb) {
    const size_t wo512 = (size_t)nb * 512 * 512;
    const size_t woqkv = (size_t)nb * 1536 * 512;
    const size_t wo1 = (size_t)nb * 2048 * 512;
    gemm_kernel<0><<<68 * 24, 256, 0, stream>>>(Xb, Wqkvb + woqkv, biascat + nb * 1536, Qb,
                                                Kb2, Vt, nullptr, 24, 512);
    attn_kernel<<<544, 256, 0, stream>>>(Qb, Kb2, Vt, Ob);
    gemm_kernel<2><<<68 * 8, 256, 0, stream>>>(Ob, Wob + wo512, bo + nb * 512, X, nullptr,
                                               nullptr, X, 8, 512);
    ln_kernel<<<MPAD, 256, 0, stream>>>(X, g1 + nb * 512, be1 + nb * 512, Xb);
    gemm_kernel<3><<<68 * 32, 256, 0, stream>>>(Xb, W1b + wo1, b1 + nb * 2048, Hm, nullptr,
                                                nullptr, nullptr, 32, 512);
    gemm_kernel<2><<<68 * 8, 256, 0, stream>>>(Hm, W2b + wo1, b2 + nb * 512, X, nullptr,
                                               nullptr, X, 8, 2048);
    ln_kernel<<<MPAD, 256, 0, stream>>>(X, g2 + nb * 512, be2 + nb * 512, Xb);
  }

  logits_kernel<<<B_ * T_, 64, 0, stream>>>(X, Wp, bp, (float*)d_out);
  memout_kernel<<<512, 256, 0, stream>>>(X, (float*)d_out + (size_t)B_ * T_ * 4);
}

// Round 8
// 818.932 us; speedup vs baseline: 1.2990x; 1.1157x over previous
//
#include <hip/hip_runtime.h>
#include <hip/hip_bf16.h>

typedef unsigned short ushort_t;
typedef __attribute__((ext_vector_type(8))) __bf16 bf16x8;
typedef __attribute__((ext_vector_type(4))) float f32x4;
typedef __attribute__((ext_vector_type(16))) float f32x16;
typedef __attribute__((ext_vector_type(2))) unsigned u32x2;
typedef __attribute__((ext_vector_type(4))) unsigned u32x4;

#define B_ 8
#define T_ 340
#define M_ 32
#define H_ 512
#define NH_ 8
#define DH_ 64
#define INFO_ 1020
#define L_ 1084
#define LP_ 1088
#define MROWS 8672
#define MPAD 8704
#define HMLP 2048

__device__ __forceinline__ ushort_t f2bf(float f) {
  unsigned u = __builtin_bit_cast(unsigned, f);
  unsigned r = (u + 0x7fffu + ((u >> 16) & 1u)) >> 16;
  return (ushort_t)r;
}

__device__ __forceinline__ unsigned cvtpk_bf16(float lo, float hi) {
  unsigned r;
  asm volatile("v_cvt_pk_bf16_f32 %0, %1, %2" : "=v"(r) : "v"(lo), "v"(hi));
  return r;
}

__device__ __forceinline__ void gload16(const ushort_t* g, ushort_t* l) {
  __builtin_amdgcn_global_load_lds((const __attribute__((address_space(1))) unsigned*)g,
                                   (__attribute__((address_space(3))) unsigned*)l, 16, 0, 0);
}

// ---------------- zero pads (Q/K l-pads, Vt l-pads, Ob row-pads) ----------------
__global__ __launch_bounds__(256) void zero_pads_kernel(ushort_t* Qb, ushort_t* Kb,
                                                        ushort_t* Vt, ushort_t* Ob) {
  int idx = blockIdx.x * 256 + threadIdx.x;
  if (idx < 16384) {
    int bh = idx >> 8;
    int rest = idx & 255;
    int l = L_ + (rest >> 6);
    int d = rest & 63;
    size_t o = ((size_t)bh * LP_ + l) * DH_ + d;
    Qb[o] = 0;
    Kb[o] = 0;
    Vt[((size_t)bh * DH_ + d) * LP_ + l] = 0;
  } else if (idx < 32768) {
    int j = idx - 16384;
    Ob[(size_t)MROWS * H_ + j] = 0;
  }
}

// ---------------- f32 -> bf16 convert, 8 elems/thread ----------------
__global__ __launch_bounds__(256) void cvt8_kernel(const float* __restrict__ src,
                                                   ushort_t* __restrict__ dst, int n8) {
  int i = blockIdx.x * 256 + threadIdx.x;
  if (i >= n8) return;
  f32x4 a = ((const f32x4*)src)[2 * i];
  f32x4 b = ((const f32x4*)src)[2 * i + 1];
  u32x4 o;
  o.x = cvtpk_bf16(a[0], a[1]);
  o.y = cvtpk_bf16(a[2], a[3]);
  o.z = cvtpk_bf16(b[0], b[1]);
  o.w = cvtpk_bf16(b[2], b[3]);
  ((u32x4*)dst)[i] = o;
}

// ---------------- Wq/Wk/Wv -> concatenated bf16 [nb][1536][512], 8/thread ----------
__global__ __launch_bounds__(256) void cvtqkv_kernel(const float* __restrict__ q,
                                                     const float* __restrict__ k,
                                                     const float* __restrict__ v,
                                                     ushort_t* __restrict__ dst) {
  int i8 = blockIdx.x * 256 + threadIdx.x;
  if (i8 >= 131072) return;  // 4*512*512/8
  int i = i8 * 8;
  int nb = i >> 18;
  int rem = i & 262143;
  size_t base8 = ((size_t)nb * 786432 + rem) >> 3;
  const float* srcs[3] = {q, k, v};
#pragma unroll
  for (int w = 0; w < 3; w++) {
    f32x4 a = ((const f32x4*)srcs[w])[2 * i8];
    f32x4 b = ((const f32x4*)srcs[w])[2 * i8 + 1];
    u32x4 o;
    o.x = cvtpk_bf16(a[0], a[1]);
    o.y = cvtpk_bf16(a[2], a[3]);
    o.z = cvtpk_bf16(b[0], b[1]);
    o.w = cvtpk_bf16(b[2], b[3]);
    ((u32x4*)dst)[base8 + (size_t)w * 32768] = o;  // 262144/8
  }
}

__global__ __launch_bounds__(256) void biascat_kernel(const float* __restrict__ bq,
                                                      const float* __restrict__ bk,
                                                      const float* __restrict__ bv,
                                                      float* __restrict__ dst) {
  int i = blockIdx.x * 256 + threadIdx.x;
  if (i < 2048) {
    int nb = i >> 9, r = i & 511;
    float* d = dst + nb * 1536;
    d[r] = bq[i];
    d[512 + r] = bk[i];
    d[1024 + r] = bv[i];
  }
}

// ---------------- embedding + initial LN ----------------
__global__ __launch_bounds__(256) void embed_ln_kernel(
    const float* __restrict__ returns, const float* __restrict__ actions,
    const float* __restrict__ t_table, const float* __restrict__ s_table,
    const float* __restrict__ Wr, const float* __restrict__ br,
    const float* __restrict__ Wa, const float* __restrict__ ba,
    const float* __restrict__ g, const float* __restrict__ be,
    const float* __restrict__ read_mem, const float* __restrict__ mem_tok,
    const int* __restrict__ states, const int* __restrict__ timestep,
    float* __restrict__ X, ushort_t* __restrict__ Xb) {
  const int row = blockIdx.x;
  const int tid = threadIdx.x;
  if (row >= MROWS) {
    Xb[(size_t)row * H_ + tid] = 0;
    Xb[(size_t)row * H_ + tid + 256] = 0;
    return;
  }
  const int b = row / L_, l = row - b * L_;
  float v[2];
#pragma unroll
  for (int s2 = 0; s2 < 2; s2++) {
    int hh = tid + s2 * 256;
    float val;
    if (l < M_) {
      val = read_mem[(size_t)l * H_ + hh];
    } else if (l >= M_ + INFO_) {
      val = mem_tok[(size_t)(l - M_ - INFO_) * H_ + hh];
    } else {
      int ii = l - M_;
      int t = ii / 3, c = ii - t * 3;
      int bt = b * T_ + t;
      if (c == 1) {
        val = s_table[(size_t)states[bt] * H_ + hh];
      } else {
        float te = t_table[(size_t)timestep[bt] * H_ + hh];
        val = (c == 0 ? returns[bt] * Wr[hh] + br[hh] : actions[bt] * Wa[hh] + ba[hh]) + te;
      }
    }
    v[s2] = val;
  }
  float sum = v[0] + v[1], sq = v[0] * v[0] + v[1] * v[1];
  __shared__ float sa[4], sb[4];
#pragma unroll
  for (int o = 1; o < 64; o <<= 1) {
    sum += __shfl_xor(sum, o);
    sq += __shfl_xor(sq, o);
  }
  int wv = tid >> 6, lane = tid & 63;
  if (lane == 0) { sa[wv] = sum; sb[wv] = sq; }
  __syncthreads();
  sum = sa[0] + sa[1] + sa[2] + sa[3];
  sq = sb[0] + sb[1] + sb[2] + sb[3];
  float mu = sum * (1.0f / H_);
  float var = sq * (1.0f / H_) - mu * mu;
  float rstd = rsqrtf(var + 1e-5f);
#pragma unroll
  for (int s2 = 0; s2 < 2; s2++) {
    int hh = tid + s2 * 256;
    float y = (v[s2] - mu) * rstd * g[hh] + be[hh];
    X[(size_t)row * H_ + hh] = y;
    Xb[(size_t)row * H_ + hh] = f2bf(y);
  }
}

// ---------------- LN over residual stream (in place) ----------------
__global__ __launch_bounds__(256) void ln_kernel(float* __restrict__ X,
                                                 const float* __restrict__ g,
                                                 const float* __restrict__ be,
                                                 ushort_t* __restrict__ Xb) {
  const int row = blockIdx.x;
  const int tid = threadIdx.x;
  if (row >= MROWS) {
    Xb[(size_t)row * H_ + tid] = 0;
    Xb[(size_t)row * H_ + tid + 256] = 0;
    return;
  }
  float v0 = X[(size_t)row * H_ + tid];
  float v1 = X[(size_t)row * H_ + tid + 256];
  float sum = v0 + v1, sq = v0 * v0 + v1 * v1;
  __shared__ float sa[4], sb[4];
#pragma unroll
  for (int o = 1; o < 64; o <<= 1) {
    sum += __shfl_xor(sum, o);
    sq += __shfl_xor(sq, o);
  }
  int wv = tid >> 6, lane = tid & 63;
  if (lane == 0) { sa[wv] = sum; sb[wv] = sq; }
  __syncthreads();
  sum = sa[0] + sa[1] + sa[2] + sa[3];
  sq = sb[0] + sb[1] + sb[2] + sb[3];
  float mu = sum * (1.0f / H_);
  float var = sq * (1.0f / H_) - mu * mu;
  float rstd = rsqrtf(var + 1e-5f);
  float y0 = (v0 - mu) * rstd * g[tid] + be[tid];
  float y1 = (v1 - mu) * rstd * g[tid + 256] + be[tid + 256];
  X[(size_t)row * H_ + tid] = y0;
  X[(size_t)row * H_ + tid + 256] = y1;
  Xb[(size_t)row * H_ + tid] = f2bf(y0);
  Xb[(size_t)row * H_ + tid + 256] = f2bf(y1);
}

// ---------------- GEMM: 128x64 tile, BK=64, dbuf LDS, counted vmcnt(6), XOR swizzle,
// chunked XCD mapping (unchanged from round 7).
template <int MODE>
__global__ __launch_bounds__(256, 3) void gemm_kernel(const ushort_t* __restrict__ A,
                                                      const ushort_t* __restrict__ W,
                                                      const float* __restrict__ bias,
                                                      void* __restrict__ o0,
                                                      void* __restrict__ o1,
                                                      void* __restrict__ o2,
                                                      const float* __restrict__ resid,
                                                      int Ntiles, int K) {
  __shared__ ushort_t As[2][8192];
  __shared__ ushort_t Bs[2][4096];
  const int tid = threadIdx.x;
  const int job = (blockIdx.x & 7) * (gridDim.x >> 3) + (blockIdx.x >> 3);
  const int bx = job % Ntiles, by = job / Ntiles;
  const int m0 = by * 128, n0 = bx * 64;
  const int lane = tid & 63, wv = tid >> 6;
  const int wr = wv >> 1, wc = wv & 1;
  f32x4 acc[4][2] = {};

  const int srow = lane >> 3;
  const int kg = (lane & 7) ^ srow;
  const ushort_t* Asrc[4];
  const ushort_t* Bsrc[2];
#pragma unroll
  for (int g2 = 0; g2 < 4; g2++) {
    int row = wv * 32 + g2 * 8 + srow;
    Asrc[g2] = A + (size_t)(m0 + row) * K + kg * 8;
  }
#pragma unroll
  for (int g2 = 0; g2 < 2; g2++) {
    int row = wv * 16 + g2 * 8 + srow;
    Bsrc[g2] = W + (size_t)(n0 + row) * K + kg * 8;
  }
  ushort_t* ldsA[2] = {&As[0][wv * 2048], &As[1][wv * 2048]};
  ushort_t* ldsB[2] = {&Bs[0][wv * 1024], &Bs[1][wv * 1024]};

  const int NT = K >> 6;

#pragma unroll
  for (int g2 = 0; g2 < 4; g2++) gload16(Asrc[g2], ldsA[0] + g2 * 512);
#pragma unroll
  for (int g2 = 0; g2 < 2; g2++) gload16(Bsrc[g2], ldsB[0] + g2 * 512);

  const int q = lane >> 4, lr = lane & 15;
  const int s0 = q ^ (lr & 7);
  const int s1 = (4 + q) ^ (lr & 7);

  auto compute_tile = [&](int cur) {
    bf16x8 af[4][2], bfr[2][2];
#pragma unroll
    for (int mi = 0; mi < 4; mi++) {
      const ushort_t* rp = &As[cur][(wr * 64 + mi * 16 + lr) * 64];
      af[mi][0] = *(const bf16x8*)(rp + s0 * 8);
      af[mi][1] = *(const bf16x8*)(rp + s1 * 8);
    }
#pragma unroll
    for (int ni = 0; ni < 2; ni++) {
      const ushort_t* rp = &Bs[cur][(wc * 32 + ni * 16 + lr) * 64];
      bfr[ni][0] = *(const bf16x8*)(rp + s0 * 8);
      bfr[ni][1] = *(const bf16x8*)(rp + s1 * 8);
    }
#pragma unroll
    for (int kc = 0; kc < 2; kc++)
#pragma unroll
      for (int mi = 0; mi < 4; mi++)
#pragma unroll
        for (int ni = 0; ni < 2; ni++)
          acc[mi][ni] =
              __builtin_amdgcn_mfma_f32_16x16x32_bf16(af[mi][kc], bfr[ni][kc], acc[mi][ni], 0, 0, 0);
  };

  for (int kt = 0; kt < NT - 1; kt++) {
    const int cur = kt & 1, nxt = cur ^ 1;
    const int k0n = (kt + 1) << 6;
#pragma unroll
    for (int g2 = 0; g2 < 4; g2++) gload16(Asrc[g2] + k0n, ldsA[nxt] + g2 * 512);
#pragma unroll
    for (int g2 = 0; g2 < 2; g2++) gload16(Bsrc[g2] + k0n, ldsB[nxt] + g2 * 512);
    asm volatile("s_waitcnt vmcnt(6)" ::: "memory");
    __builtin_amdgcn_s_barrier();
    asm volatile("" ::: "memory");
    compute_tile(cur);
    asm volatile("" ::: "memory");
    __builtin_amdgcn_s_barrier();
  }
  {
    asm volatile("s_waitcnt vmcnt(0)" ::: "memory");
    __builtin_amdgcn_s_barrier();
    asm volatile("" ::: "memory");
    compute_tile((NT - 1) & 1);
  }

#pragma unroll
  for (int mi = 0; mi < 4; mi++) {
#pragma unroll
    for (int ni = 0; ni < 2; ni++) {
#pragma unroll
      for (int r = 0; r < 4; r++) {
        int m = m0 + wr * 64 + mi * 16 + ((lane >> 4) << 2) + r;
        int n = n0 + wc * 32 + ni * 16 + (lane & 15);
        float val = acc[mi][ni][r] + bias[n];
        if (MODE == 0) {
          if (m < MROWS) {
            int b = m / L_;
            int l = m - b * L_;
            int which = n >> 9, nn = n & 511;
            int hh = nn >> 6, d = nn & 63;
            if (which == 0) {
              val *= 0.18033688011112043f;  // fold 0.125*log2(e) into Q
              ((ushort_t*)o0)[(((size_t)(b * NH_ + hh)) * LP_ + l) * DH_ + d] = f2bf(val);
            } else if (which == 1)
              ((ushort_t*)o1)[(((size_t)(b * NH_ + hh)) * LP_ + l) * DH_ + d] = f2bf(val);
            else
              ((ushort_t*)o2)[(((size_t)(b * NH_ + hh)) * DH_ + d) * LP_ + l] = f2bf(val);
          }
        } else if (MODE == 2) {
          if (m < MROWS) {
            size_t off = (size_t)m * H_ + n;
            ((float*)o0)[off] = resid[off] + val;
          }
        } else {
          float ge = 0.5f * val * (1.0f + erff(val * 0.70710678f));
          ((ushort_t*)o0)[(size_t)m * HMLP + n] = f2bf(ge);
        }
      }
    }
  }
}

// ---------------- flash attention v4: block = 4 waves, ONE bh, 4 consecutive tiles ----
// K/V chunks staged once per block into LDS via coalesced global_load_lds
// (pre-swizzled source, swizzled ds_read), double-buffered, counted vmcnt.
// bid -> xcd = bid&7; slot = bid>>3 (0..71); g = slot>>3 (0..8), bhi = slot&7;
// bh = (bhi<<3)|xcd  (same-bh blocks pinned to one XCD's L2); wave tile t = 33-4g-wv.
__global__ __launch_bounds__(256, 3) void attn_kernel(const ushort_t* __restrict__ Qb,
                                                      const ushort_t* __restrict__ Kb,
                                                      const ushort_t* __restrict__ Vt,
                                                      ushort_t* __restrict__ Ob) {
  __shared__ ushort_t Klds[2][2048];  // 32 rows x 64 el, XOR-swizzled in 16B slots
  __shared__ ushort_t Vlds[2][2048];  // 64 rows x 32 el, XOR-swizzled
  const int tid = threadIdx.x;
  const int lane = tid & 63, wv = tid >> 6;
  const int xcd = blockIdx.x & 7, slot = blockIdx.x >> 3;
  const int g = slot >> 3, bhi = slot & 7;
  const int bh = (bhi << 3) | xcd;
  const int t = 33 - 4 * g - wv;
  const bool active = (t >= 0);
  const int b = bh >> 3, h = bh & 7;
  const int qb = t * 32;
  const int lq = lane & 31, hi = lane >> 5;
  const int nk_own = active ? ((t == 33) ? 34 : (t + 1)) : 0;
  const int nkmax = (g == 0) ? 34 : (34 - 4 * g);
  const int cmask = (t == 0) ? -1 : (nk_own - 1);
  const int i = qb + lq;

  const ushort_t* Qp = Qb + (size_t)bh * LP_ * DH_;
  const ushort_t* Kp = Kb + (size_t)bh * LP_ * DH_;
  const ushort_t* Vp = Vt + (size_t)bh * DH_ * LP_;

  // staging source addresses (per-lane, pre-swizzled; chunk c adds c*2048 (K) / c*32 (V))
  const ushort_t* KsrcB = Kp + (size_t)(8 * wv + (lane >> 3)) * DH_ + (((lane & 7) ^ ((lane >> 3) & 7)) * 8);
  const ushort_t* VsrcB = Vp + (size_t)(16 * wv + (lane >> 2)) * LP_ + (((lane & 3) ^ ((lane >> 3) & 3)) * 8);
  ushort_t* KdstA = &Klds[0][wv * 512];
  ushort_t* KdstB = &Klds[1][wv * 512];
  ushort_t* VdstA = &Vlds[0][wv * 512];
  ushort_t* VdstB = &Vlds[1][wv * 512];

  // Q fragments (one-time)
  bf16x8 qf[4];
  if (active) {
#pragma unroll
    for (int dc = 0; dc < 4; dc++)
      qf[dc] = *(const bf16x8*)(Qp + (size_t)(qb + lq) * DH_ + dc * 16 + hi * 8);
  }
  asm volatile("s_waitcnt vmcnt(0)" ::: "memory");

  f32x16 o0 = {}, o1 = {};
  float lsum = 0.f;

  // read-side swizzled LDS element offsets
  int koff[4], voff[4];
#pragma unroll
  for (int dc = 0; dc < 4; dc++) koff[dc] = lq * 64 + (((dc * 2 + hi) ^ (lq & 7)) * 8);
#pragma unroll
  for (int f = 0; f < 4; f++) {
    int dt = f >> 1, cc = f & 1;
    voff[f] = (dt * 32 + lq) * 32 + ((((cc * 2 + hi) ^ ((lq >> 1) & 3))) * 8);
  }

  // prologue: stage chunk 0 into buf 0
  gload16(KsrcB, KdstA);
  gload16(VsrcB, VdstA);

  for (int c = 0; c < nkmax; c++) {
    const int cur = c & 1;
    const bool more = (c + 1 < nkmax);
    if (more) {
      const ushort_t* ks = KsrcB + (size_t)(c + 1) * 2048;
      const ushort_t* vs = VsrcB + (c + 1) * 32;
      if (cur) {
        gload16(ks, KdstA);
        gload16(vs, VdstA);
      } else {
        gload16(ks, KdstB);
        gload16(vs, VdstB);
      }
      asm volatile("s_waitcnt vmcnt(2)" ::: "memory");
    } else {
      asm volatile("s_waitcnt vmcnt(0)" ::: "memory");
    }
    __builtin_amdgcn_s_barrier();
    asm volatile("" ::: "memory");

    if (c < nk_own) {
      bf16x8 kf[4], vf[4];
#pragma unroll
      for (int dc = 0; dc < 4; dc++) kf[dc] = *(const bf16x8*)&Klds[cur][koff[dc]];
#pragma unroll
      for (int f = 0; f < 4; f++) vf[f] = *(const bf16x8*)&Vlds[cur][voff[f]];

      f32x16 s = {};
#pragma unroll
      for (int dc = 0; dc < 4; dc++)
        s = __builtin_amdgcn_mfma_f32_32x32x16_bf16(kf[dc], qf[dc], s, 0, 0, 0);
      float p[16];
      if (c == cmask) {
#pragma unroll
        for (int r = 0; r < 16; r++) {
          int jcol = c * 32 + (r & 3) + 8 * (r >> 2) + 4 * hi;
          bool ok = (jcol < L_) && ((jcol < M_) || (i >= M_ + INFO_) || (jcol <= i));
          p[r] = ok ? __builtin_amdgcn_exp2f(s[r]) : 0.f;
        }
      } else {
#pragma unroll
        for (int r = 0; r < 16; r++) p[r] = __builtin_amdgcn_exp2f(s[r]);
      }
      float u0 = (p[0] + p[1]) + (p[2] + p[3]);
      float u1 = (p[4] + p[5]) + (p[6] + p[7]);
      float u2 = (p[8] + p[9]) + (p[10] + p[11]);
      float u3 = (p[12] + p[13]) + (p[14] + p[15]);
      lsum += (u0 + u1) + (u2 + u3);
      bf16x8 pf[2];
#pragma unroll
      for (int cc = 0; cc < 2; cc++) {
        unsigned A01 = cvtpk_bf16(p[8 * cc + 0], p[8 * cc + 1]);
        unsigned A23 = cvtpk_bf16(p[8 * cc + 2], p[8 * cc + 3]);
        unsigned B45 = cvtpk_bf16(p[8 * cc + 4], p[8 * cc + 5]);
        unsigned B67 = cvtpk_bf16(p[8 * cc + 6], p[8 * cc + 7]);
        u32x2 r0 = __builtin_amdgcn_permlane32_swap(A01, B45, false, false);
        u32x2 r1 = __builtin_amdgcn_permlane32_swap(A23, B67, false, false);
        u32x4 w = {r0.x, r1.x, r0.y, r1.y};
        pf[cc] = __builtin_bit_cast(bf16x8, w);
      }
      o0 = __builtin_amdgcn_mfma_f32_32x32x16_bf16(vf[0], pf[0], o0, 0, 0, 0);
      o0 = __builtin_amdgcn_mfma_f32_32x32x16_bf16(vf[1], pf[1], o0, 0, 0, 0);
      o1 = __builtin_amdgcn_mfma_f32_32x32x16_bf16(vf[2], pf[0], o1, 0, 0, 0);
      o1 = __builtin_amdgcn_mfma_f32_32x32x16_bf16(vf[3], pf[1], o1, 0, 0, 0);
    }
    asm volatile("" ::: "memory");
    __builtin_amdgcn_s_barrier();
  }

  if (active) {
    u32x2 tt = __builtin_amdgcn_permlane32_swap(__builtin_bit_cast(unsigned, lsum),
                                                __builtin_bit_cast(unsigned, lsum), false, false);
    lsum = __builtin_bit_cast(float, tt.x) + __builtin_bit_cast(float, tt.y);
    if (i < L_) {
      const float inv = 1.0f / lsum;
      ushort_t* orow = Ob + ((size_t)(b * L_ + i)) * H_ + h * DH_;
#pragma unroll
      for (int dt = 0; dt < 2; dt++) {
#pragma unroll
        for (int q2 = 0; q2 < 4; q2++) {
          float v0 = (dt ? o1[4 * q2 + 0] : o0[4 * q2 + 0]) * inv;
          float v1 = (dt ? o1[4 * q2 + 1] : o0[4 * q2 + 1]) * inv;
          float v2 = (dt ? o1[4 * q2 + 2] : o0[4 * q2 + 2]) * inv;
          float v3 = (dt ? o1[4 * q2 + 3] : o0[4 * q2 + 3]) * inv;
          int dbase = dt * 32 + 8 * q2 + 4 * hi;
          *(unsigned*)(orow + dbase) = cvtpk_bf16(v0, v1);
          *(unsigned*)(orow + dbase + 2) = cvtpk_bf16(v2, v3);
        }
      }
    }
  }
}

// ---------------- heads ----------------
__global__ __launch_bounds__(64) void logits_kernel(const float* __restrict__ X,
                                                    const float* __restrict__ Wp,
                                                    const float* __restrict__ bp,
                                                    float* __restrict__ out) {
  const int bt = blockIdx.x;
  const int b = bt / T_, t = bt - b * T_;
  const int lane = threadIdx.x;
  const float* xr = X + ((size_t)(b * L_ + M_ + 3 * t + 1)) * H_ + lane * 8;
  float x0[8];
#pragma unroll
  for (int ii = 0; ii < 8; ii++) x0[ii] = xr[ii];
#pragma unroll
  for (int a = 0; a < 4; a++) {
    const float* wr2 = Wp + (size_t)a * H_ + lane * 8;
    float p = 0.f;
#pragma unroll
    for (int ii = 0; ii < 8; ii++) p += x0[ii] * wr2[ii];
#pragma unroll
    for (int o = 1; o < 64; o <<= 1) p += __shfl_xor(p, o);
    if (lane == 0) out[(size_t)bt * 4 + a] = p + bp[a];
  }
}

__global__ __launch_bounds__(256) void memout_kernel(const float* __restrict__ X,
                                                     float* __restrict__ out) {
  int idx = blockIdx.x * 256 + threadIdx.x;
  if (idx < B_ * M_ * H_) {
    int b = idx >> 14;
    int rest = idx & 16383;
    int r = rest >> 9;
    int hh = rest & 511;
    out[idx] = X[((size_t)(b * L_ + M_ + INFO_ + r)) * H_ + hh];
  }
}

// ---------------- launcher ----------------
extern "C" void kernel_launch(void* const* d_in, const int* in_sizes, int n_in, void* d_out,
                              int out_size, void* d_ws, size_t ws_size, hipStream_t stream) {
  const float* returns = (const float*)d_in[0];
  const float* actions = (const float*)d_in[1];
  const float* t_table = (const float*)d_in[2];
  const float* s_table = (const float*)d_in[3];
  const float* Wr = (const float*)d_in[4];
  const float* br = (const float*)d_in[5];
  const float* Wa = (const float*)d_in[6];
  const float* ba = (const float*)d_in[7];
  const float* ln_e_g = (const float*)d_in[8];
  const float* ln_e_b = (const float*)d_in[9];
  const float* read_mem = (const float*)d_in[10];
  const float* mem_tok = (const float*)d_in[11];
  const float* Wq = (const float*)d_in[12];
  const float* bq = (const float*)d_in[13];
  const float* Wk = (const float*)d_in[14];
  const float* bk = (const float*)d_in[15];
  const float* Wv = (const float*)d_in[16];
  const float* bv = (const float*)d_in[17];
  const float* Wo = (const float*)d_in[18];
  const float* bo = (const float*)d_in[19];
  const float* W1 = (const float*)d_in[20];
  const float* b1 = (const float*)d_in[21];
  const float* W2 = (const float*)d_in[22];
  const float* b2 = (const float*)d_in[23];
  const float* g1 = (const float*)d_in[24];
  const float* be1 = (const float*)d_in[25];
  const float* g2 = (const float*)d_in[26];
  const float* be2 = (const float*)d_in[27];
  const float* Wp = (const float*)d_in[28];
  const float* bp = (const float*)d_in[29];
  const int* states = (const int*)d_in[30];
  const int* timestep = (const int*)d_in[31];

  char* ws = (char*)d_ws;
  size_t off = 0;
  auto alloc = [&](size_t bytes) -> char* {
    char* p = ws + off;
    off += (bytes + 255) & ~(size_t)255;
    return p;
  };
  float* X = (float*)alloc((size_t)MPAD * H_ * 4);
  ushort_t* Xb = (ushort_t*)alloc((size_t)MPAD * H_ * 2);
  ushort_t* Qb = (ushort_t*)alloc((size_t)B_ * NH_ * LP_ * DH_ * 2);
  ushort_t* Kb2 = (ushort_t*)alloc((size_t)B_ * NH_ * LP_ * DH_ * 2);
  ushort_t* Vt = (ushort_t*)alloc((size_t)B_ * NH_ * DH_ * LP_ * 2);
  ushort_t* Ob = (ushort_t*)alloc((size_t)MPAD * H_ * 2);
  ushort_t* Hm = (ushort_t*)alloc((size_t)MPAD * HMLP * 2);
  ushort_t* Wqkvb = (ushort_t*)alloc((size_t)4 * 1536 * 512 * 2);
  ushort_t* Wob = (ushort_t*)alloc((size_t)4 * 512 * 512 * 2);
  ushort_t* W1b = (ushort_t*)alloc((size_t)4 * 2048 * 512 * 2);
  ushort_t* W2b = (ushort_t*)alloc((size_t)4 * 512 * 2048 * 2);
  float* biascat = (float*)alloc((size_t)4 * 1536 * 4);

  zero_pads_kernel<<<128, 256, 0, stream>>>(Qb, Kb2, Vt, Ob);
  cvtqkv_kernel<<<512, 256, 0, stream>>>(Wq, Wk, Wv, Wqkvb);
  biascat_kernel<<<8, 256, 0, stream>>>(bq, bk, bv, biascat);
  cvt8_kernel<<<512, 256, 0, stream>>>(Wo, Wob, 4 * 512 * 512 / 8);
  cvt8_kernel<<<2048, 256, 0, stream>>>(W1, W1b, 4 * 2048 * 512 / 8);
  cvt8_kernel<<<2048, 256, 0, stream>>>(W2, W2b, 4 * 512 * 2048 / 8);

  embed_ln_kernel<<<MPAD, 256, 0, stream>>>(returns, actions, t_table, s_table, Wr, br, Wa,
                                            ba, ln_e_g, ln_e_b, read_mem, mem_tok, states,
                                            timestep, X, Xb);

  for (int nb = 0; nb < 4; ++nb) {
    const size_t wo512 = (size_t)nb * 512 * 512;
    const size_t woqkv = (size_t)nb * 1536 * 512;
    const size_t wo1 = (size_t)nb * 2048 * 512;
    gemm_kernel<0><<<68 * 24, 256, 0, stream>>>(Xb, Wqkvb + woqkv, biascat + nb * 1536, Qb,
                                                Kb2, Vt, nullptr, 24, 512);
    attn_kernel<<<576, 256, 0, stream>>>(Qb, Kb2, Vt, Ob);
    gemm_kernel<2><<<68 * 8, 256, 0, stream>>>(Ob, Wob + wo512, bo + nb * 512, X, nullptr,
                                               nullptr, X, 8, 512);
    ln_kernel<<<MPAD, 256, 0, stream>>>(X, g1 + nb * 512, be1 + nb * 512, Xb);
    gemm_kernel<3><<<68 * 32, 256, 0, stream>>>(Xb, W1b + wo1, b1 + nb * 2048, Hm, nullptr,
                                                nullptr, nullptr, 32, 512);
    gemm_kernel<2><<<68 * 8, 256, 0, stream>>>(Hm, W2b + wo1, b2 + nb * 512, X, nullptr,
                                               nullptr, X, 8, 2048);
    ln_kernel<<<MPAD, 256, 0, stream>>>(X, g2 + nb * 512, be2 + nb * 512, Xb);
  }

  logits_kernel<<<B_ * T_, 64, 0, stream>>>(X, Wp, bp, (float*)d_out);
  memout_kernel<<<512, 256, 0, stream>>>(X, (float*)d_out + (size_t)B_ * T_ * 4);
}

// Round 9
// 627.028 us; speedup vs baseline: 1.6966x; 1.3061x over previous
//
#include <hip/hip_runtime.h>
#include <hip/hip_bf16.h>

typedef unsigned short ushort_t;
typedef __attribute__((ext_vector_type(8))) __bf16 bf16x8;
typedef __attribute__((ext_vector_type(4))) float f32x4;
typedef __attribute__((ext_vector_type(16))) float f32x16;
typedef __attribute__((ext_vector_type(2))) unsigned u32x2;
typedef __attribute__((ext_vector_type(4))) unsigned u32x4;

#define B_ 8
#define T_ 340
#define M_ 32
#define H_ 512
#define NH_ 8
#define DH_ 64
#define INFO_ 1020
#define L_ 1084
#define LP_ 1088
#define MROWS 8672
#define MPAD 8704
#define HMLP 2048

__device__ __forceinline__ ushort_t f2bf(float f) {
  unsigned u = __builtin_bit_cast(unsigned, f);
  unsigned r = (u + 0x7fffu + ((u >> 16) & 1u)) >> 16;
  return (ushort_t)r;
}

__device__ __forceinline__ float bflo(unsigned u) {
  return __builtin_bit_cast(float, u << 16);
}
__device__ __forceinline__ float bfhi(unsigned u) {
  return __builtin_bit_cast(float, u & 0xffff0000u);
}

__device__ __forceinline__ unsigned cvtpk_bf16(float lo, float hi) {
  unsigned r;
  asm volatile("v_cvt_pk_bf16_f32 %0, %1, %2" : "=v"(r) : "v"(lo), "v"(hi));
  return r;
}

__device__ __forceinline__ void gload16(const ushort_t* g, ushort_t* l) {
  __builtin_amdgcn_global_load_lds((const __attribute__((address_space(1))) unsigned*)g,
                                   (__attribute__((address_space(3))) unsigned*)l, 16, 0, 0);
}

// ---------------- zero pads (Q/K l-pads, Vt l-pads, Ob row-pads) ----------------
__global__ __launch_bounds__(256) void zero_pads_kernel(ushort_t* Qb, ushort_t* Kb,
                                                        ushort_t* Vt, ushort_t* Ob) {
  int idx = blockIdx.x * 256 + threadIdx.x;
  if (idx < 16384) {
    int bh = idx >> 8;
    int rest = idx & 255;
    int l = L_ + (rest >> 6);
    int d = rest & 63;
    size_t o = ((size_t)bh * LP_ + l) * DH_ + d;
    Qb[o] = 0;
    Kb[o] = 0;
    Vt[((size_t)bh * DH_ + d) * LP_ + l] = 0;
  } else if (idx < 32768) {
    int j = idx - 16384;
    Ob[(size_t)MROWS * H_ + j] = 0;
  }
}

// ---------------- f32 -> bf16 convert, 8 elems/thread ----------------
__global__ __launch_bounds__(256) void cvt8_kernel(const float* __restrict__ src,
                                                   ushort_t* __restrict__ dst, int n8) {
  int i = blockIdx.x * 256 + threadIdx.x;
  if (i >= n8) return;
  f32x4 a = ((const f32x4*)src)[2 * i];
  f32x4 b = ((const f32x4*)src)[2 * i + 1];
  u32x4 o;
  o.x = cvtpk_bf16(a[0], a[1]);
  o.y = cvtpk_bf16(a[2], a[3]);
  o.z = cvtpk_bf16(b[0], b[1]);
  o.w = cvtpk_bf16(b[2], b[3]);
  ((u32x4*)dst)[i] = o;
}

// ---------------- Wq/Wk/Wv -> concatenated bf16 [nb][1536][512], 8/thread ----------
__global__ __launch_bounds__(256) void cvtqkv_kernel(const float* __restrict__ q,
                                                     const float* __restrict__ k,
                                                     const float* __restrict__ v,
                                                     ushort_t* __restrict__ dst) {
  int i8 = blockIdx.x * 256 + threadIdx.x;
  if (i8 >= 131072) return;  // 4*512*512/8
  int i = i8 * 8;
  int nb = i >> 18;
  int rem = i & 262143;
  size_t base8 = ((size_t)nb * 786432 + rem) >> 3;
  const float* srcs[3] = {q, k, v};
#pragma unroll
  for (int w = 0; w < 3; w++) {
    f32x4 a = ((const f32x4*)srcs[w])[2 * i8];
    f32x4 b = ((const f32x4*)srcs[w])[2 * i8 + 1];
    u32x4 o;
    o.x = cvtpk_bf16(a[0], a[1]);
    o.y = cvtpk_bf16(a[2], a[3]);
    o.z = cvtpk_bf16(b[0], b[1]);
    o.w = cvtpk_bf16(b[2], b[3]);
    ((u32x4*)dst)[base8 + (size_t)w * 32768] = o;  // 262144/8
  }
}

__global__ __launch_bounds__(256) void biascat_kernel(const float* __restrict__ bq,
                                                      const float* __restrict__ bk,
                                                      const float* __restrict__ bv,
                                                      float* __restrict__ dst) {
  int i = blockIdx.x * 256 + threadIdx.x;
  if (i < 2048) {
    int nb = i >> 9, r = i & 511;
    float* d = dst + nb * 1536;
    d[r] = bq[i];
    d[512 + r] = bk[i];
    d[1024 + r] = bv[i];
  }
}

// ---------------- embedding + initial LN (bf16 residual out) ----------------
__global__ __launch_bounds__(256) void embed_ln_kernel(
    const float* __restrict__ returns, const float* __restrict__ actions,
    const float* __restrict__ t_table, const float* __restrict__ s_table,
    const float* __restrict__ Wr, const float* __restrict__ br,
    const float* __restrict__ Wa, const float* __restrict__ ba,
    const float* __restrict__ g, const float* __restrict__ be,
    const float* __restrict__ read_mem, const float* __restrict__ mem_tok,
    const int* __restrict__ states, const int* __restrict__ timestep,
    ushort_t* __restrict__ Xb) {
  const int row = blockIdx.x;
  const int tid = threadIdx.x;
  if (row >= MROWS) {
    Xb[(size_t)row * H_ + tid] = 0;
    Xb[(size_t)row * H_ + tid + 256] = 0;
    return;
  }
  const int b = row / L_, l = row - b * L_;
  float v[2];
#pragma unroll
  for (int s2 = 0; s2 < 2; s2++) {
    int hh = tid + s2 * 256;
    float val;
    if (l < M_) {
      val = read_mem[(size_t)l * H_ + hh];
    } else if (l >= M_ + INFO_) {
      val = mem_tok[(size_t)(l - M_ - INFO_) * H_ + hh];
    } else {
      int ii = l - M_;
      int t = ii / 3, c = ii - t * 3;
      int bt = b * T_ + t;
      if (c == 1) {
        val = s_table[(size_t)states[bt] * H_ + hh];
      } else {
        float te = t_table[(size_t)timestep[bt] * H_ + hh];
        val = (c == 0 ? returns[bt] * Wr[hh] + br[hh] : actions[bt] * Wa[hh] + ba[hh]) + te;
      }
    }
    v[s2] = val;
  }
  float sum = v[0] + v[1], sq = v[0] * v[0] + v[1] * v[1];
  __shared__ float sa[4], sb[4];
#pragma unroll
  for (int o = 1; o < 64; o <<= 1) {
    sum += __shfl_xor(sum, o);
    sq += __shfl_xor(sq, o);
  }
  int wv = tid >> 6, lane = tid & 63;
  if (lane == 0) { sa[wv] = sum; sb[wv] = sq; }
  __syncthreads();
  sum = sa[0] + sa[1] + sa[2] + sa[3];
  sq = sb[0] + sb[1] + sb[2] + sb[3];
  float mu = sum * (1.0f / H_);
  float var = sq * (1.0f / H_) - mu * mu;
  float rstd = rsqrtf(var + 1e-5f);
#pragma unroll
  for (int s2 = 0; s2 < 2; s2++) {
    int hh = tid + s2 * 256;
    float y = (v[s2] - mu) * rstd * g[hh] + be[hh];
    Xb[(size_t)row * H_ + hh] = f2bf(y);
  }
}

// ---------------- fused residual-add + LN, bf16 in-place ----------------
// Xb = LN(Xb + Y), per row; pad rows zeroed.
__global__ __launch_bounds__(256) void ln_add_kernel(ushort_t* __restrict__ Xb,
                                                     const ushort_t* __restrict__ Y,
                                                     const float* __restrict__ g,
                                                     const float* __restrict__ be) {
  const int row = blockIdx.x;
  const int tid = threadIdx.x;
  unsigned* xr = (unsigned*)(Xb + (size_t)row * H_);
  if (row >= MROWS) {
    xr[tid] = 0;
    return;
  }
  const unsigned* yr = (const unsigned*)(Y + (size_t)row * H_);
  unsigned xu = xr[tid], yu = yr[tid];
  float v0 = bflo(xu) + bflo(yu);
  float v1 = bfhi(xu) + bfhi(yu);
  float sum = v0 + v1, sq = v0 * v0 + v1 * v1;
  __shared__ float sa[4], sb[4];
#pragma unroll
  for (int o = 1; o < 64; o <<= 1) {
    sum += __shfl_xor(sum, o);
    sq += __shfl_xor(sq, o);
  }
  int wv = tid >> 6, lane = tid & 63;
  if (lane == 0) { sa[wv] = sum; sb[wv] = sq; }
  __syncthreads();
  sum = sa[0] + sa[1] + sa[2] + sa[3];
  sq = sb[0] + sb[1] + sb[2] + sb[3];
  float mu = sum * (1.0f / H_);
  float var = sq * (1.0f / H_) - mu * mu;
  float rstd = rsqrtf(var + 1e-5f);
  float g0 = g[2 * tid], g1v = g[2 * tid + 1];
  float b0 = be[2 * tid], b1v = be[2 * tid + 1];
  float n0 = (v0 - mu) * rstd * g0 + b0;
  float n1 = (v1 - mu) * rstd * g1v + b1v;
  xr[tid] = cvtpk_bf16(n0, n1);
}

// ---------------- GEMM: 128x64 tile, BK=64, dbuf LDS, counted vmcnt(6), XOR swizzle,
// chunked XCD mapping.
// MODE 0: fused QKV, N=1536 -> Q(scaled)->(b,h,l,d), K->(b,h,l,d), V packed->(b,h,d,l)
// MODE 2: bf16 o0[m,n] = acc + bias          (Y for fused resid+LN)
// MODE 3: bf16 o0[m,n] = gelu(acc + bias), N=2048
template <int MODE>
__global__ __launch_bounds__(256, 3) void gemm_kernel(const ushort_t* __restrict__ A,
                                                      const ushort_t* __restrict__ W,
                                                      const float* __restrict__ bias,
                                                      void* __restrict__ o0,
                                                      void* __restrict__ o1,
                                                      void* __restrict__ o2, int Ntiles,
                                                      int K) {
  __shared__ ushort_t As[2][8192];
  __shared__ ushort_t Bs[2][4096];
  const int tid = threadIdx.x;
  const int job = (blockIdx.x & 7) * (gridDim.x >> 3) + (blockIdx.x >> 3);
  const int bx = job % Ntiles, by = job / Ntiles;
  const int m0 = by * 128, n0 = bx * 64;
  const int lane = tid & 63, wv = tid >> 6;
  const int wr = wv >> 1, wc = wv & 1;
  f32x4 acc[4][2] = {};

  const int srow = lane >> 3;
  const int kg = (lane & 7) ^ srow;
  const ushort_t* Asrc[4];
  const ushort_t* Bsrc[2];
#pragma unroll
  for (int g2 = 0; g2 < 4; g2++) {
    int row = wv * 32 + g2 * 8 + srow;
    Asrc[g2] = A + (size_t)(m0 + row) * K + kg * 8;
  }
#pragma unroll
  for (int g2 = 0; g2 < 2; g2++) {
    int row = wv * 16 + g2 * 8 + srow;
    Bsrc[g2] = W + (size_t)(n0 + row) * K + kg * 8;
  }
  ushort_t* ldsA[2] = {&As[0][wv * 2048], &As[1][wv * 2048]};
  ushort_t* ldsB[2] = {&Bs[0][wv * 1024], &Bs[1][wv * 1024]};

  const int NT = K >> 6;

#pragma unroll
  for (int g2 = 0; g2 < 4; g2++) gload16(Asrc[g2], ldsA[0] + g2 * 512);
#pragma unroll
  for (int g2 = 0; g2 < 2; g2++) gload16(Bsrc[g2], ldsB[0] + g2 * 512);

  const int q = lane >> 4, lr = lane & 15;
  const int s0 = q ^ (lr & 7);
  const int s1 = (4 + q) ^ (lr & 7);

  auto compute_tile = [&](int cur) {
    bf16x8 af[4][2], bfr[2][2];
#pragma unroll
    for (int mi = 0; mi < 4; mi++) {
      const ushort_t* rp = &As[cur][(wr * 64 + mi * 16 + lr) * 64];
      af[mi][0] = *(const bf16x8*)(rp + s0 * 8);
      af[mi][1] = *(const bf16x8*)(rp + s1 * 8);
    }
#pragma unroll
    for (int ni = 0; ni < 2; ni++) {
      const ushort_t* rp = &Bs[cur][(wc * 32 + ni * 16 + lr) * 64];
      bfr[ni][0] = *(const bf16x8*)(rp + s0 * 8);
      bfr[ni][1] = *(const bf16x8*)(rp + s1 * 8);
    }
#pragma unroll
    for (int kc = 0; kc < 2; kc++)
#pragma unroll
      for (int mi = 0; mi < 4; mi++)
#pragma unroll
        for (int ni = 0; ni < 2; ni++)
          acc[mi][ni] =
              __builtin_amdgcn_mfma_f32_16x16x32_bf16(af[mi][kc], bfr[ni][kc], acc[mi][ni], 0, 0, 0);
  };

  for (int kt = 0; kt < NT - 1; kt++) {
    const int cur = kt & 1, nxt = cur ^ 1;
    const int k0n = (kt + 1) << 6;
#pragma unroll
    for (int g2 = 0; g2 < 4; g2++) gload16(Asrc[g2] + k0n, ldsA[nxt] + g2 * 512);
#pragma unroll
    for (int g2 = 0; g2 < 2; g2++) gload16(Bsrc[g2] + k0n, ldsB[nxt] + g2 * 512);
    asm volatile("s_waitcnt vmcnt(6)" ::: "memory");
    __builtin_amdgcn_s_barrier();
    asm volatile("" ::: "memory");
    compute_tile(cur);
    asm volatile("" ::: "memory");
    __builtin_amdgcn_s_barrier();
  }
  {
    asm volatile("s_waitcnt vmcnt(0)" ::: "memory");
    __builtin_amdgcn_s_barrier();
    asm volatile("" ::: "memory");
    compute_tile((NT - 1) & 1);
  }

  // epilogue: 4-row groups are 4-aligned; L_=1084 and MROWS are multiples of 4,
  // so a group never crosses a batch boundary or the MROWS edge.
#pragma unroll
  for (int mi = 0; mi < 4; mi++) {
    const int mbase = m0 + wr * 64 + mi * 16 + ((lane >> 4) << 2);
    const bool mok = mbase < MROWS;
    int bb = 0, lbase = 0;
    if (MODE == 0) {
      bb = mbase / L_;
      lbase = mbase - bb * L_;
    }
#pragma unroll
    for (int ni = 0; ni < 2; ni++) {
      const int n = n0 + wc * 32 + ni * 16 + (lane & 15);
      float v[4];
#pragma unroll
      for (int r = 0; r < 4; r++) v[r] = acc[mi][ni][r] + bias[n];
      if (MODE == 0) {
        if (mok) {
          const int which = n >> 9, nn = n & 511;
          const int hh = nn >> 6, d = nn & 63;
          if (which == 0) {
            ushort_t* o = (ushort_t*)o0 + (((size_t)(bb * NH_ + hh)) * LP_ + lbase) * DH_ + d;
#pragma unroll
            for (int r = 0; r < 4; r++)
              o[(size_t)r * DH_] = f2bf(v[r] * 0.18033688011112043f);
          } else if (which == 1) {
            ushort_t* o = (ushort_t*)o1 + (((size_t)(bb * NH_ + hh)) * LP_ + lbase) * DH_ + d;
#pragma unroll
            for (int r = 0; r < 4; r++) o[(size_t)r * DH_] = f2bf(v[r]);
          } else {
            u32x2 w2;
            w2.x = cvtpk_bf16(v[0], v[1]);
            w2.y = cvtpk_bf16(v[2], v[3]);
            *(u32x2*)((ushort_t*)o2 + (((size_t)(bb * NH_ + hh)) * DH_ + d) * LP_ + lbase) = w2;
          }
        }
      } else if (MODE == 2) {
        if (mok) {
#pragma unroll
          for (int r = 0; r < 4; r++)
            ((ushort_t*)o0)[(size_t)(mbase + r) * H_ + n] = f2bf(v[r]);
        }
      } else {
#pragma unroll
        for (int r = 0; r < 4; r++) {
          float ge = 0.5f * v[r] * (1.0f + erff(v[r] * 0.70710678f));
          ((ushort_t*)o0)[(size_t)(mbase + r) * HMLP + n] = f2bf(ge);
        }
      }
    }
  }
}

// ---------------- flash attention v4 (unchanged from round 8) ----------------
__global__ __launch_bounds__(256, 3) void attn_kernel(const ushort_t* __restrict__ Qb,
                                                      const ushort_t* __restrict__ Kb,
                                                      const ushort_t* __restrict__ Vt,
                                                      ushort_t* __restrict__ Ob) {
  __shared__ ushort_t Klds[2][2048];
  __shared__ ushort_t Vlds[2][2048];
  const int tid = threadIdx.x;
  const int lane = tid & 63, wv = tid >> 6;
  const int xcd = blockIdx.x & 7, slot = blockIdx.x >> 3;
  const int g = slot >> 3, bhi = slot & 7;
  const int bh = (bhi << 3) | xcd;
  const int t = 33 - 4 * g - wv;
  const bool active = (t >= 0);
  const int b = bh >> 3, h = bh & 7;
  const int qb = t * 32;
  const int lq = lane & 31, hi = lane >> 5;
  const int nk_own = active ? ((t == 33) ? 34 : (t + 1)) : 0;
  const int nkmax = (g == 0) ? 34 : (34 - 4 * g);
  const int cmask = (t == 0) ? -1 : (nk_own - 1);
  const int i = qb + lq;

  const ushort_t* Qp = Qb + (size_t)bh * LP_ * DH_;
  const ushort_t* Kp = Kb + (size_t)bh * LP_ * DH_;
  const ushort_t* Vp = Vt + (size_t)bh * DH_ * LP_;

  const ushort_t* KsrcB =
      Kp + (size_t)(8 * wv + (lane >> 3)) * DH_ + (((lane & 7) ^ ((lane >> 3) & 7)) * 8);
  const ushort_t* VsrcB =
      Vp + (size_t)(16 * wv + (lane >> 2)) * LP_ + (((lane & 3) ^ ((lane >> 3) & 3)) * 8);
  ushort_t* KdstA = &Klds[0][wv * 512];
  ushort_t* KdstB = &Klds[1][wv * 512];
  ushort_t* VdstA = &Vlds[0][wv * 512];
  ushort_t* VdstB = &Vlds[1][wv * 512];

  bf16x8 qf[4];
  if (active) {
#pragma unroll
    for (int dc = 0; dc < 4; dc++)
      qf[dc] = *(const bf16x8*)(Qp + (size_t)(qb + lq) * DH_ + dc * 16 + hi * 8);
  }
  asm volatile("s_waitcnt vmcnt(0)" ::: "memory");

  f32x16 o0 = {}, o1 = {};
  float lsum = 0.f;

  int koff[4], voff[4];
#pragma unroll
  for (int dc = 0; dc < 4; dc++) koff[dc] = lq * 64 + (((dc * 2 + hi) ^ (lq & 7)) * 8);
#pragma unroll
  for (int f = 0; f < 4; f++) {
    int dt = f >> 1, cc = f & 1;
    voff[f] = (dt * 32 + lq) * 32 + ((((cc * 2 + hi) ^ ((lq >> 1) & 3))) * 8);
  }

  gload16(KsrcB, KdstA);
  gload16(VsrcB, VdstA);

  for (int c = 0; c < nkmax; c++) {
    const int cur = c & 1;
    const bool more = (c + 1 < nkmax);
    if (more) {
      const ushort_t* ks = KsrcB + (size_t)(c + 1) * 2048;
      const ushort_t* vs = VsrcB + (c + 1) * 32;
      if (cur) {
        gload16(ks, KdstA);
        gload16(vs, VdstA);
      } else {
        gload16(ks, KdstB);
        gload16(vs, VdstB);
      }
      asm volatile("s_waitcnt vmcnt(2)" ::: "memory");
    } else {
      asm volatile("s_waitcnt vmcnt(0)" ::: "memory");
    }
    __builtin_amdgcn_s_barrier();
    asm volatile("" ::: "memory");

    if (c < nk_own) {
      bf16x8 kf[4], vf[4];
#pragma unroll
      for (int dc = 0; dc < 4; dc++) kf[dc] = *(const bf16x8*)&Klds[cur][koff[dc]];
#pragma unroll
      for (int f = 0; f < 4; f++) vf[f] = *(const bf16x8*)&Vlds[cur][voff[f]];

      f32x16 s = {};
#pragma unroll
      for (int dc = 0; dc < 4; dc++)
        s = __builtin_amdgcn_mfma_f32_32x32x16_bf16(kf[dc], qf[dc], s, 0, 0, 0);
      float p[16];
      if (c == cmask) {
#pragma unroll
        for (int r = 0; r < 16; r++) {
          int jcol = c * 32 + (r & 3) + 8 * (r >> 2) + 4 * hi;
          bool ok = (jcol < L_) && ((jcol < M_) || (i >= M_ + INFO_) || (jcol <= i));
          p[r] = ok ? __builtin_amdgcn_exp2f(s[r]) : 0.f;
        }
      } else {
#pragma unroll
        for (int r = 0; r < 16; r++) p[r] = __builtin_amdgcn_exp2f(s[r]);
      }
      float u0 = (p[0] + p[1]) + (p[2] + p[3]);
      float u1 = (p[4] + p[5]) + (p[6] + p[7]);
      float u2 = (p[8] + p[9]) + (p[10] + p[11]);
      float u3 = (p[12] + p[13]) + (p[14] + p[15]);
      lsum += (u0 + u1) + (u2 + u3);
      bf16x8 pf[2];
#pragma unroll
      for (int cc = 0; cc < 2; cc++) {
        unsigned A01 = cvtpk_bf16(p[8 * cc + 0], p[8 * cc + 1]);
        unsigned A23 = cvtpk_bf16(p[8 * cc + 2], p[8 * cc + 3]);
        unsigned B45 = cvtpk_bf16(p[8 * cc + 4], p[8 * cc + 5]);
        unsigned B67 = cvtpk_bf16(p[8 * cc + 6], p[8 * cc + 7]);
        u32x2 r0 = __builtin_amdgcn_permlane32_swap(A01, B45, false, false);
        u32x2 r1 = __builtin_amdgcn_permlane32_swap(A23, B67, false, false);
        u32x4 w = {r0.x, r1.x, r0.y, r1.y};
        pf[cc] = __builtin_bit_cast(bf16x8, w);
      }
      o0 = __builtin_amdgcn_mfma_f32_32x32x16_bf16(vf[0], pf[0], o0, 0, 0, 0);
      o0 = __builtin_amdgcn_mfma_f32_32x32x16_bf16(vf[1], pf[1], o0, 0, 0, 0);
      o1 = __builtin_amdgcn_mfma_f32_32x32x16_bf16(vf[2], pf[0], o1, 0, 0, 0);
      o1 = __builtin_amdgcn_mfma_f32_32x32x16_bf16(vf[3], pf[1], o1, 0, 0, 0);
    }
    asm volatile("" ::: "memory");
    __builtin_amdgcn_s_barrier();
  }

  if (active) {
    u32x2 tt = __builtin_amdgcn_permlane32_swap(__builtin_bit_cast(unsigned, lsum),
                                                __builtin_bit_cast(unsigned, lsum), false, false);
    lsum = __builtin_bit_cast(float, tt.x) + __builtin_bit_cast(float, tt.y);
    if (i < L_) {
      const float inv = 1.0f / lsum;
      ushort_t* orow = Ob + ((size_t)(b * L_ + i)) * H_ + h * DH_;
#pragma unroll
      for (int dt = 0; dt < 2; dt++) {
#pragma unroll
        for (int q2 = 0; q2 < 4; q2++) {
          float v0 = (dt ? o1[4 * q2 + 0] : o0[4 * q2 + 0]) * inv;
          float v1 = (dt ? o1[4 * q2 + 1] : o0[4 * q2 + 1]) * inv;
          float v2 = (dt ? o1[4 * q2 + 2] : o0[4 * q2 + 2]) * inv;
          float v3 = (dt ? o1[4 * q2 + 3] : o0[4 * q2 + 3]) * inv;
          int dbase = dt * 32 + 8 * q2 + 4 * hi;
          *(unsigned*)(orow + dbase) = cvtpk_bf16(v0, v1);
          *(unsigned*)(orow + dbase + 2) = cvtpk_bf16(v2, v3);
        }
      }
    }
  }
}

// ---------------- heads (bf16 residual input) ----------------
__global__ __launch_bounds__(64) void logits_kernel(const ushort_t* __restrict__ Xb,
                                                    const float* __restrict__ Wp,
                                                    const float* __restrict__ bp,
                                                    float* __restrict__ out) {
  const int bt = blockIdx.x;
  const int b = bt / T_, t = bt - b * T_;
  const int lane = threadIdx.x;
  const ushort_t* xr = Xb + ((size_t)(b * L_ + M_ + 3 * t + 1)) * H_ + lane * 8;
  u32x4 xv = *(const u32x4*)xr;
  float x0[8];
#pragma unroll
  for (int ii = 0; ii < 4; ii++) {
    unsigned u = xv[ii];
    x0[2 * ii] = bflo(u);
    x0[2 * ii + 1] = bfhi(u);
  }
#pragma unroll
  for (int a = 0; a < 4; a++) {
    const float* wr2 = Wp + (size_t)a * H_ + lane * 8;
    float p = 0.f;
#pragma unroll
    for (int ii = 0; ii < 8; ii++) p += x0[ii] * wr2[ii];
#pragma unroll
    for (int o = 1; o < 64; o <<= 1) p += __shfl_xor(p, o);
    if (lane == 0) out[(size_t)bt * 4 + a] = p + bp[a];
  }
}

__global__ __launch_bounds__(256) void memout_kernel(const ushort_t* __restrict__ Xb,
                                                     float* __restrict__ out) {
  int idx = blockIdx.x * 256 + threadIdx.x;
  if (idx < B_ * M_ * H_ / 2) {
    int e = idx * 2;
    int b = e >> 14;
    int rest = e & 16383;
    int r = rest >> 9;
    int hh = rest & 511;
    unsigned u = *(const unsigned*)&Xb[((size_t)(b * L_ + M_ + INFO_ + r)) * H_ + hh];
    out[e] = bflo(u);
    out[e + 1] = bfhi(u);
  }
}

// ---------------- launcher ----------------
extern "C" void kernel_launch(void* const* d_in, const int* in_sizes, int n_in, void* d_out,
                              int out_size, void* d_ws, size_t ws_size, hipStream_t stream) {
  const float* returns = (const float*)d_in[0];
  const float* actions = (const float*)d_in[1];
  const float* t_table = (const float*)d_in[2];
  const float* s_table = (const float*)d_in[3];
  const float* Wr = (const float*)d_in[4];
  const float* br = (const float*)d_in[5];
  const float* Wa = (const float*)d_in[6];
  const float* ba = (const float*)d_in[7];
  const float* ln_e_g = (const float*)d_in[8];
  const float* ln_e_b = (const float*)d_in[9];
  const float* read_mem = (const float*)d_in[10];
  const float* mem_tok = (const float*)d_in[11];
  const float* Wq = (const float*)d_in[12];
  const float* bq = (const float*)d_in[13];
  const float* Wk = (const float*)d_in[14];
  const float* bk = (const float*)d_in[15];
  const float* Wv = (const float*)d_in[16];
  const float* bv = (const float*)d_in[17];
  const float* Wo = (const float*)d_in[18];
  const float* bo = (const float*)d_in[19];
  const float* W1 = (const float*)d_in[20];
  const float* b1 = (const float*)d_in[21];
  const float* W2 = (const float*)d_in[22];
  const float* b2 = (const float*)d_in[23];
  const float* g1 = (const float*)d_in[24];
  const float* be1 = (const float*)d_in[25];
  const float* g2 = (const float*)d_in[26];
  const float* be2 = (const float*)d_in[27];
  const float* Wp = (const float*)d_in[28];
  const float* bp = (const float*)d_in[29];
  const int* states = (const int*)d_in[30];
  const int* timestep = (const int*)d_in[31];

  char* ws = (char*)d_ws;
  size_t off = 0;
  auto alloc = [&](size_t bytes) -> char* {
    char* p = ws + off;
    off += (bytes + 255) & ~(size_t)255;
    return p;
  };
  ushort_t* Xb = (ushort_t*)alloc((size_t)MPAD * H_ * 2);
  ushort_t* Y = (ushort_t*)alloc((size_t)MPAD * H_ * 2);
  ushort_t* Qb = (ushort_t*)alloc((size_t)B_ * NH_ * LP_ * DH_ * 2);
  ushort_t* Kb2 = (ushort_t*)alloc((size_t)B_ * NH_ * LP_ * DH_ * 2);
  ushort_t* Vt = (ushort_t*)alloc((size_t)B_ * NH_ * DH_ * LP_ * 2);
  ushort_t* Ob = (ushort_t*)alloc((size_t)MPAD * H_ * 2);
  ushort_t* Hm = (ushort_t*)alloc((size_t)MPAD * HMLP * 2);
  ushort_t* Wqkvb = (ushort_t*)alloc((size_t)4 * 1536 * 512 * 2);
  ushort_t* Wob = (ushort_t*)alloc((size_t)4 * 512 * 512 * 2);
  ushort_t* W1b = (ushort_t*)alloc((size_t)4 * 2048 * 512 * 2);
  ushort_t* W2b = (ushort_t*)alloc((size_t)4 * 512 * 2048 * 2);
  float* biascat = (float*)alloc((size_t)4 * 1536 * 4);

  zero_pads_kernel<<<128, 256, 0, stream>>>(Qb, Kb2, Vt, Ob);
  cvtqkv_kernel<<<512, 256, 0, stream>>>(Wq, Wk, Wv, Wqkvb);
  biascat_kernel<<<8, 256, 0, stream>>>(bq, bk, bv, biascat);
  cvt8_kernel<<<512, 256, 0, stream>>>(Wo, Wob, 4 * 512 * 512 / 8);
  cvt8_kernel<<<2048, 256, 0, stream>>>(W1, W1b, 4 * 2048 * 512 / 8);
  cvt8_kernel<<<2048, 256, 0, stream>>>(W2, W2b, 4 * 512 * 2048 / 8);

  embed_ln_kernel<<<MPAD, 256, 0, stream>>>(returns, actions, t_table, s_table, Wr, br, Wa,
                                            ba, ln_e_g, ln_e_b, read_mem, mem_tok, states,
                                            timestep, Xb);

  for (int nb = 0; nb < 4; ++nb) {
    const size_t wo512 = (size_t)nb * 512 * 512;
    const size_t woqkv = (size_t)nb * 1536 * 512;
    const size_t wo1 = (size_t)nb * 2048 * 512;
    gemm_kernel<0><<<68 * 24, 256, 0, stream>>>(Xb, Wqkvb + woqkv, biascat + nb * 1536, Qb,
                                                Kb2, Vt, 24, 512);
    attn_kernel<<<576, 256, 0, stream>>>(Qb, Kb2, Vt, Ob);
    gemm_kernel<2><<<68 * 8, 256, 0, stream>>>(Ob, Wob + wo512, bo + nb * 512, Y, nullptr,
                                               nullptr, 8, 512);
    ln_add_kernel<<<MPAD, 256, 0, stream>>>(Xb, Y, g1 + nb * 512, be1 + nb * 512);
    gemm_kernel<3><<<68 * 32, 256, 0, stream>>>(Xb, W1b + wo1, b1 + nb * 2048, Hm, nullptr,
                                                nullptr, 32, 512);
    gemm_kernel<2><<<68 * 8, 256, 0, stream>>>(Hm, W2b + wo1, b2 + nb * 512, Y, nullptr,
                                               nullptr, 8, 2048);
    ln_add_kernel<<<MPAD, 256, 0, stream>>>(Xb, Y, g2 + nb * 512, be2 + nb * 512);
  }

  logits_kernel<<<B_ * T_, 64, 0, stream>>>(Xb, Wp, bp, (float*)d_out);
  memout_kernel<<<256, 256, 0, stream>>>(Xb, (float*)d_out + (size_t)B_ * T_ * 4);
}